// Round 2
// baseline (11777.616 us; speedup 1.0000x reference)
//
#include <hip/hip_runtime.h>
#include <hip/hip_bf16.h>
#include <cfloat>
#include <cstdio>

#define TT   2048
#define BB   64
#define DMD  128
#define CDD  32
#define NCH  512
#define FEATN 418
#define LDW  33     // padded leading dim for 128x32 LDS tiles in scan
#define APITCH 130  // front A-tile pitch
#define YPITCH 257  // front Y-tile pitch

// ---------------- helpers ----------------
__device__ __forceinline__ float redx16(float v) {
  v += __shfl_xor(v, 1); v += __shfl_xor(v, 2);
  v += __shfl_xor(v, 4); v += __shfl_xor(v, 8);
  return v;
}
__device__ __forceinline__ float redx32(float v) { v = redx16(v); v += __shfl_xor(v, 16); return v; }
__device__ __forceinline__ float redx64(float v) { v = redx32(v); v += __shfl_xor(v, 32); return v; }
__device__ __forceinline__ float bfbits2f(unsigned int u) {
  union { unsigned int i; float f; } v; v.i = u << 16; return v.f;
}
__device__ __forceinline__ unsigned short f2bf(float f) {
  union { float f; unsigned int i; } u; u.f = f;
  unsigned int r = u.i + 0x7FFFu + ((u.i >> 16) & 1u);
  return (unsigned short)(r >> 16);
}
__device__ __forceinline__ float sigmoidf_(float x) { return 1.f / (1.f + expf(-x)); }

__device__ __forceinline__ void load_cand8(const unsigned short* cand, size_t idx, float* pf) {
  uint4 v = *reinterpret_cast<const uint4*>(cand + idx);
  pf[0] = bfbits2f(v.x & 0xFFFFu); pf[1] = bfbits2f(v.x >> 16);
  pf[2] = bfbits2f(v.y & 0xFFFFu); pf[3] = bfbits2f(v.y >> 16);
  pf[4] = bfbits2f(v.z & 0xFFFFu); pf[5] = bfbits2f(v.z >> 16);
  pf[6] = bfbits2f(v.w & 0xFFFFu); pf[7] = bfbits2f(v.w >> 16);
}

// ============================================================================
// k_front: per 32-position tile: embed+LN -> conv3/5+GLU -> op+residual+LN ->
// chunk means, validity, surface partials, ln(u)@wcu, u@wg. No global
// intermediates except chunk-level outputs.
// grid (64 tiles, 64 batches) x 256 threads. LDS ~59.9 KB.
// ============================================================================
__global__ __launch_bounds__(256) void k_front(
    const int* __restrict__ tokens, const float* __restrict__ emb,
    const float* __restrict__ inw, const float* __restrict__ inb,
    const float* __restrict__ c1w, const float* __restrict__ c1b,
    const float* __restrict__ c2w, const float* __restrict__ c2b,
    const float* __restrict__ opw, const float* __restrict__ opb,
    const float* __restrict__ onw, const float* __restrict__ onb,
    const float* __restrict__ unw, const float* __restrict__ unb,
    const float* __restrict__ wcu, const float* __restrict__ wgv,
    float* __restrict__ chunk_h, float* __restrict__ validf,
    float* __restrict__ lgu, float* __restrict__ gu,
    float* __restrict__ spsum, float* __restrict__ spmax, float* __restrict__ spcnt) {
  __shared__ float A[36 * APITCH];   // x tile rows t0-2..t0+33
  __shared__ float Y[32 * YPITCH];   // y12 tile; later reused for partials/lnu
  __shared__ float Wl[2048];         // weight staging
  __shared__ float tokm[32];
  const int b = blockIdx.y, tile = blockIdx.x;
  const int t0 = tile * 32;
  const int t = threadIdx.x;
  const int lane = t & 63, wv = t >> 6;

  // ---- phase 0: embed + input LN into A (zero pad outside sequence) ----
  for (int r = wv; r < 36; r += 4) {
    int p = t0 + r - 2;
    float2 o = make_float2(0.f, 0.f);
    if (p >= 0 && p < TT) {
      int tok = tokens[b * TT + p];
      if (lane == 0 && r >= 2 && r < 34) tokm[r - 2] = (tok != 0) ? 1.f : 0.f;
      float2 e = *reinterpret_cast<const float2*>(emb + (size_t)tok * DMD + lane * 2);
      float mean = redx64(e.x + e.y) * (1.f / 128.f);
      float d0 = e.x - mean, d1 = e.y - mean;
      float vvv = redx64(d0 * d0 + d1 * d1) * (1.f / 128.f);
      float rs = rsqrtf(vvv + 1e-5f);
      o.x = d0 * rs * inw[lane * 2]     + inb[lane * 2];
      o.y = d1 * rs * inw[lane * 2 + 1] + inb[lane * 2 + 1];
    }
    *reinterpret_cast<float2*>(&A[r * APITCH + lane * 2]) = o;
  }
  const int tm = t >> 4, tn = t & 15;
  const int r0 = tm * 2;
  float acc[2][16];

  // ---- phase 1a: conv3 + GLU -> Y cols 0..127 ----
  #pragma unroll
  for (int m = 0; m < 2; ++m)
    #pragma unroll
    for (int q = 0; q < 16; ++q) acc[m][q] = 0.f;
  for (int k0 = 0; k0 < 384; k0 += 8) {
    __syncthreads();
    {
      int kk = t >> 5, oo = (t & 31) * 8;
      *reinterpret_cast<float4*>(&Wl[kk * 256 + oo])     = *reinterpret_cast<const float4*>(&c1w[(size_t)(k0 + kk) * 256 + oo]);
      *reinterpret_cast<float4*>(&Wl[kk * 256 + oo + 4]) = *reinterpret_cast<const float4*>(&c1w[(size_t)(k0 + kk) * 256 + oo + 4]);
    }
    __syncthreads();
    #pragma unroll
    for (int kk = 0; kk < 8; ++kk) {
      int k = k0 + kk, tap = k >> 7, ii = k & 127;
      float a0 = A[(r0 + tap + 1) * APITCH + ii];
      float a1 = A[(r0 + tap + 2) * APITCH + ii];
      float w16[16];
      *reinterpret_cast<float4*>(&w16[0])  = *reinterpret_cast<float4*>(&Wl[kk * 256 + tn * 8]);
      *reinterpret_cast<float4*>(&w16[4])  = *reinterpret_cast<float4*>(&Wl[kk * 256 + tn * 8 + 4]);
      *reinterpret_cast<float4*>(&w16[8])  = *reinterpret_cast<float4*>(&Wl[kk * 256 + 128 + tn * 8]);
      *reinterpret_cast<float4*>(&w16[12]) = *reinterpret_cast<float4*>(&Wl[kk * 256 + 128 + tn * 8 + 4]);
      #pragma unroll
      for (int q = 0; q < 16; ++q) { acc[0][q] += a0 * w16[q]; acc[1][q] += a1 * w16[q]; }
    }
  }
  #pragma unroll
  for (int m = 0; m < 2; ++m)
    #pragma unroll
    for (int q = 0; q < 8; ++q) {
      float av = acc[m][q]     + c1b[tn * 8 + q];
      float gv = acc[m][q + 8] + c1b[128 + tn * 8 + q];
      Y[(r0 + m) * YPITCH + tn * 8 + q] = av * sigmoidf_(gv);
    }

  // ---- phase 1b: conv5 + GLU -> Y cols 128..255 ----
  #pragma unroll
  for (int m = 0; m < 2; ++m)
    #pragma unroll
    for (int q = 0; q < 16; ++q) acc[m][q] = 0.f;
  for (int k0 = 0; k0 < 640; k0 += 8) {
    __syncthreads();
    {
      int kk = t >> 5, oo = (t & 31) * 8;
      *reinterpret_cast<float4*>(&Wl[kk * 256 + oo])     = *reinterpret_cast<const float4*>(&c2w[(size_t)(k0 + kk) * 256 + oo]);
      *reinterpret_cast<float4*>(&Wl[kk * 256 + oo + 4]) = *reinterpret_cast<const float4*>(&c2w[(size_t)(k0 + kk) * 256 + oo + 4]);
    }
    __syncthreads();
    #pragma unroll
    for (int kk = 0; kk < 8; ++kk) {
      int k = k0 + kk, tap = k >> 7, ii = k & 127;
      float a0 = A[(r0 + tap) * APITCH + ii];
      float a1 = A[(r0 + tap + 1) * APITCH + ii];
      float w16[16];
      *reinterpret_cast<float4*>(&w16[0])  = *reinterpret_cast<float4*>(&Wl[kk * 256 + tn * 8]);
      *reinterpret_cast<float4*>(&w16[4])  = *reinterpret_cast<float4*>(&Wl[kk * 256 + tn * 8 + 4]);
      *reinterpret_cast<float4*>(&w16[8])  = *reinterpret_cast<float4*>(&Wl[kk * 256 + 128 + tn * 8]);
      *reinterpret_cast<float4*>(&w16[12]) = *reinterpret_cast<float4*>(&Wl[kk * 256 + 128 + tn * 8 + 4]);
      #pragma unroll
      for (int q = 0; q < 16; ++q) { acc[0][q] += a0 * w16[q]; acc[1][q] += a1 * w16[q]; }
    }
  }
  #pragma unroll
  for (int m = 0; m < 2; ++m)
    #pragma unroll
    for (int q = 0; q < 8; ++q) {
      float av = acc[m][q]     + c2b[tn * 8 + q];
      float gv = acc[m][q + 8] + c2b[128 + tn * 8 + q];
      Y[(r0 + m) * YPITCH + 128 + tn * 8 + q] = av * sigmoidf_(gv);
    }

  // ---- phase 2: op GEMM (Y @ op_w) + residual + LN -> h (registers) ----
  float acc2[2][8] = {};
  for (int k0 = 0; k0 < 256; k0 += 16) {
    __syncthreads();
    {
      int kc = t >> 4, oo = (t & 15) * 8;
      *reinterpret_cast<float4*>(&Wl[kc * 128 + oo])     = *reinterpret_cast<const float4*>(&opw[(size_t)(k0 + kc) * 128 + oo]);
      *reinterpret_cast<float4*>(&Wl[kc * 128 + oo + 4]) = *reinterpret_cast<const float4*>(&opw[(size_t)(k0 + kc) * 128 + oo + 4]);
    }
    __syncthreads();
    #pragma unroll
    for (int kc = 0; kc < 16; ++kc) {
      int k = k0 + kc;
      float y0 = Y[r0 * YPITCH + k];
      float y1 = Y[(r0 + 1) * YPITCH + k];
      float w8[8];
      *reinterpret_cast<float4*>(&w8[0]) = *reinterpret_cast<float4*>(&Wl[kc * 128 + tn * 8]);
      *reinterpret_cast<float4*>(&w8[4]) = *reinterpret_cast<float4*>(&Wl[kc * 128 + tn * 8 + 4]);
      #pragma unroll
      for (int q = 0; q < 8; ++q) { acc2[0][q] += y0 * w8[q]; acc2[1][q] += y1 * w8[q]; }
    }
  }
  __syncthreads();  // all Y reads complete; Y region reusable

  const int col = tn * 8;
  float hreg[2][8];
  float msk[2];
  #pragma unroll
  for (int m = 0; m < 2; ++m) {
    int row = r0 + m;
    float vals[8]; float s = 0.f;
    const float* xr = &A[(row + 2) * APITCH + col];
    #pragma unroll
    for (int q = 0; q < 8; ++q) { vals[q] = acc2[m][q] + opb[col + q] + xr[q]; s += vals[q]; }
    s = redx16(s);
    float mean = s * (1.f / 128.f);
    float vv2 = 0.f;
    #pragma unroll
    for (int q = 0; q < 8; ++q) { float d = vals[q] - mean; vv2 += d * d; }
    vv2 = redx16(vv2) * (1.f / 128.f);
    float rs = rsqrtf(vv2 + 1e-5f);
    #pragma unroll
    for (int q = 0; q < 8; ++q) hreg[m][q] = (vals[q] - mean) * rs * onw[col + q] + onb[col + q];
    msk[m] = tokm[row];
  }

  // ---- phase 3: surface partials + chunk means + lgu/gu ----
  float* partS = Y;               // 16*128
  float* partM = Y + 2048;        // 16*128
  float* lnus  = Y + 4096;        // 8*128
  float ps[8], pm[8];
  #pragma unroll
  for (int q = 0; q < 8; ++q) {
    ps[q] = msk[0] * hreg[0][q] + msk[1] * hreg[1][q];
    float m0 = (msk[0] != 0.f) ? hreg[0][q] : -FLT_MAX;
    float m1 = (msk[1] != 0.f) ? hreg[1][q] : -FLT_MAX;
    pm[q] = fmaxf(m0, m1);
  }
  #pragma unroll
  for (int q = 0; q < 8; ++q) { partS[tm * 128 + col + q] = ps[q]; partM[tm * 128 + col + q] = pm[q]; }

  float ccnt = msk[0] + msk[1];
  float csum[8];
  #pragma unroll
  for (int q = 0; q < 8; ++q) csum[q] = ps[q];
  #pragma unroll
  for (int q = 0; q < 8; ++q) csum[q] += __shfl_xor(csum[q], 16);
  ccnt += __shfl_xor(ccnt, 16);

  if ((tm & 1) == 0) {
    int jg = tile * 8 + (tm >> 1);
    float inv = 1.f / fmaxf(ccnt, 1.f);
    float cm[8];
    #pragma unroll
    for (int q = 0; q < 8; ++q) cm[q] = csum[q] * inv;
    *reinterpret_cast<float4*>(&chunk_h[((size_t)b * NCH + jg) * DMD + col])     = *reinterpret_cast<float4*>(&cm[0]);
    *reinterpret_cast<float4*>(&chunk_h[((size_t)b * NCH + jg) * DMD + col + 4]) = *reinterpret_cast<float4*>(&cm[4]);
    if (tn == 0) validf[jg * BB + b] = (ccnt > 0.f) ? 1.f : 0.f;
    float gp = 0.f;
    #pragma unroll
    for (int q = 0; q < 8; ++q) gp += cm[q] * wgv[col + q];
    gp = redx16(gp);
    if (tn == 0) gu[(size_t)jg * BB + b] = gp;
    float s2 = 0.f;
    #pragma unroll
    for (int q = 0; q < 8; ++q) s2 += cm[q];
    s2 = redx16(s2);
    float mean2 = s2 * (1.f / 128.f);
    float v3 = 0.f;
    #pragma unroll
    for (int q = 0; q < 8; ++q) { float d = cm[q] - mean2; v3 += d * d; }
    v3 = redx16(v3) * (1.f / 128.f);
    float rs2 = rsqrtf(v3 + 1e-5f);
    int ch = tm >> 1;
    #pragma unroll
    for (int q = 0; q < 8; ++q) lnus[ch * 128 + col + q] = (cm[q] - mean2) * rs2 * unw[col + q] + unb[col + q];
  }
  __syncthreads();
  // lgu: 8 chunks x 32 outputs, one thread per (chunk, outcol)
  {
    int ch = t >> 5, o = t & 31;
    float accl = 0.f;
    for (int d = 0; d < 128; ++d) accl += lnus[ch * 128 + d] * wcu[d * 32 + o];
    int jg2 = tile * 8 + ch;
    lgu[((size_t)jg2 * BB + b) * 32 + o] = accl;
  }
  if (t < 128) {
    float s3 = 0.f, m3 = -FLT_MAX;
    #pragma unroll
    for (int g = 0; g < 16; ++g) { s3 += partS[g * 128 + t]; m3 = fmaxf(m3, partM[g * 128 + t]); }
    spsum[((size_t)b * 64 + tile) * DMD + t] = s3;
    spmax[((size_t)b * 64 + tile) * DMD + t] = m3;
  }
  if (t == 128) {
    float cnt = 0.f;
    for (int r = 0; r < 32; ++r) cnt += tokm[r];
    spcnt[b * 64 + tile] = cnt;
  }
}

// ---------------- surface finalize ----------------
__global__ __launch_bounds__(128) void k_surface(
    const float* __restrict__ spsum, const float* __restrict__ spmax, const float* __restrict__ spcnt,
    float* __restrict__ smean, float* __restrict__ smax) {
  const int b = blockIdx.x, d = threadIdx.x;
  float s = 0.f, m = -FLT_MAX, cnt = 0.f;
  for (int p = 0; p < 64; ++p) {
    s += spsum[((size_t)b * 64 + p) * DMD + d];
    m = fmaxf(m, spmax[((size_t)b * 64 + p) * DMD + d]);
    cnt += spcnt[b * 64 + p];
  }
  smean[b * DMD + d] = s / fmaxf(cnt, 1.f);
  smax[b * DMD + d] = (cnt > 0.f) ? m : 0.f;
}

// ---------------- cand_u = chunk_h @ wcdu + (bcdu + bcdc), bf16, segmented ----
__global__ __launch_bounds__(256) void k_cand(
    const float* __restrict__ chunk_h, const float* __restrict__ wcdu,
    const float* __restrict__ bcdu, const float* __restrict__ bcdc,
    unsigned short* __restrict__ cand, int j0) {
  __shared__ float A[64 * 132];
  __shared__ float Wl[16 * 128];
  const int lj = blockIdx.y;
  const int j = j0 + lj;
  const int n0 = blockIdx.x * 128;
  {
    int m = threadIdx.x >> 2, ks = (threadIdx.x & 3) * 32;
    const float* src = chunk_h + ((size_t)m * NCH + j) * DMD + ks;
    #pragma unroll
    for (int q = 0; q < 32; q += 4)
      *reinterpret_cast<float4*>(&A[m * 132 + ks + q]) = *reinterpret_cast<const float4*>(&src[q]);
  }
  const int tm = threadIdx.x >> 4, tn = threadIdx.x & 15;
  float acc[4][8] = {};
  for (int k0 = 0; k0 < 128; k0 += 16) {
    __syncthreads();
    {
      int kc = threadIdx.x >> 4, oo = (threadIdx.x & 15) * 8;
      *reinterpret_cast<float4*>(&Wl[kc * 128 + oo])     = *reinterpret_cast<const float4*>(&wcdu[(size_t)(k0 + kc) * 4096 + n0 + oo]);
      *reinterpret_cast<float4*>(&Wl[kc * 128 + oo + 4]) = *reinterpret_cast<const float4*>(&wcdu[(size_t)(k0 + kc) * 4096 + n0 + oo + 4]);
    }
    __syncthreads();
    #pragma unroll
    for (int kc = 0; kc < 16; ++kc) {
      int k = k0 + kc;
      float a0 = A[(tm * 4 + 0) * 132 + k];
      float a1 = A[(tm * 4 + 1) * 132 + k];
      float a2 = A[(tm * 4 + 2) * 132 + k];
      float a3 = A[(tm * 4 + 3) * 132 + k];
      float w8[8];
      *reinterpret_cast<float4*>(&w8[0]) = *reinterpret_cast<float4*>(&Wl[kc * 128 + tn * 8]);
      *reinterpret_cast<float4*>(&w8[4]) = *reinterpret_cast<float4*>(&Wl[kc * 128 + tn * 8 + 4]);
      #pragma unroll
      for (int q = 0; q < 8; ++q) {
        acc[0][q] += a0 * w8[q]; acc[1][q] += a1 * w8[q];
        acc[2][q] += a2 * w8[q]; acc[3][q] += a3 * w8[q];
      }
    }
  }
  const int colb = n0 + tn * 8;
  float bsum[8];
  #pragma unroll
  for (int q = 0; q < 8; ++q) bsum[q] = bcdu[colb + q] + bcdc[colb + q];
  #pragma unroll
  for (int r = 0; r < 4; ++r) {
    int bb2 = tm * 4 + r;
    size_t o = ((size_t)lj * BB + bb2) * 4096 + colb;
    unsigned short tmp[8];
    #pragma unroll
    for (int q = 0; q < 8; ++q) tmp[q] = f2bf(acc[r][q] + bsum[q]);
    uint4 pk;
    pk.x = (unsigned int)tmp[0] | ((unsigned int)tmp[1] << 16);
    pk.y = (unsigned int)tmp[2] | ((unsigned int)tmp[3] << 16);
    pk.z = (unsigned int)tmp[4] | ((unsigned int)tmp[5] << 16);
    pk.w = (unsigned int)tmp[6] | ((unsigned int)tmp[7] << 16);
    *reinterpret_cast<uint4*>(&cand[o]) = pk;
  }
}

// ============================================================================
// k_scan_seg: steps [j0, j0+slen) of the recurrence. One block per batch.
// State (D, P, c) persists in global between segments. Final segment runs head.
// ============================================================================
__global__ __launch_bounds__(512) void k_scan_seg(
    const float* __restrict__ chunk_h, const float* __restrict__ lgu_g,
    const float* __restrict__ gu_g, const float* __restrict__ validf,
    const unsigned short* __restrict__ cand, int j0, int slen,
    const float* __restrict__ wcc, const float* __restrict__ wcdc,
    const float* __restrict__ wg, const float* __restrict__ bg,
    const float* __restrict__ cnw, const float* __restrict__ cnb,
    const float* __restrict__ base_D,
    float* __restrict__ Dst, float* __restrict__ Pst, float* __restrict__ cst,
    const float* __restrict__ smean, const float* __restrict__ smax,
    const float* __restrict__ clw, const float* __restrict__ clb,
    const float* __restrict__ f1w, const float* __restrict__ f1b,
    const float* __restrict__ f2w, const float* __restrict__ f2b,
    float* __restrict__ out) {
  __shared__ float Dl[DMD * LDW];
  __shared__ float Pl[DMD * LDW];
  __shared__ float Cl[DMD * LDW];
  __shared__ float u_l[DMD];
  __shared__ float r_l[DMD];
  __shared__ float a_l[CDD];
  __shared__ float c_l[CDD];
  __shared__ float wcc_l[CDD * CDD];
  __shared__ float wgc_l[CDD];
  __shared__ float red[16];
  __shared__ float dotc_l;
  __shared__ int sel_i[8];
  __shared__ float sel_w[8];
  __shared__ float feat[FEATN + 2];
  __shared__ float featn[FEATN + 2];
  __shared__ float h1[256];

  const int b = blockIdx.x;
  const int t = threadIdx.x;
  const int c = t >> 4;     // column 0..31
  const int rg = t & 15;    // row group: rows rg+16m
  const bool doInit = (j0 == 0);
  const bool doHead = (j0 + slen >= NCH);

  for (int i = t; i < CDD * CDD; i += 512) wcc_l[i] = wcc[i];
  if (t < CDD) { wgc_l[t] = wg[DMD + t]; }
  if (doInit) {
    if (t < CDD) c_l[t] = 0.f;
    for (int i = t; i < DMD * LDW; i += 512) Pl[i] = 0.f;
    for (int i = t; i < DMD * CDD; i += 512) Dl[(i >> 5) * LDW + (i & 31)] = base_D[i];
  } else {
    if (t < CDD) c_l[t] = cst[b * CDD + t];
    for (int i = t; i < DMD * CDD; i += 512) {
      Dl[(i >> 5) * LDW + (i & 31)] = Dst[(size_t)b * 4096 + i];
      Pl[(i >> 5) * LDW + (i & 31)] = Pst[(size_t)b * 4096 + i];
    }
  }
  float cnw_r = 0.f, cnb_r = 0.f;
  if (t < CDD) { cnw_r = cnw[t]; cnb_r = cnb[t]; }
  const float wge = wg[160];
  const float bgs = bg[0];
  __syncthreads();
  if (doInit) {  // D0 = l2norm(base_D) per column
    float vals[8]; float s = 0.f;
    #pragma unroll
    for (int m = 0; m < 8; ++m) { int dd = rg + 16 * m; vals[m] = Dl[dd * LDW + c]; s += vals[m] * vals[m]; }
    s = redx16(s);
    float inv = 1.f / fmaxf(sqrtf(s), 1e-12f);
    #pragma unroll
    for (int m = 0; m < 8; ++m) { int dd = rg + 16 * m; Dl[dd * LDW + c] = vals[m] * inv; }
  }
  // prologue prefetch
  float pf[8];
  load_cand8(cand, ((size_t)0 * BB + b) * 4096 + (size_t)t * 8, pf);
  float un_r = (t < DMD) ? chunk_h[((size_t)b * NCH + j0) * DMD + t] : 0.f;
  float vld_n = validf[j0 * BB + b];
  float gu_n = gu_g[j0 * BB + b];
  float lgu_n = (t < 64) ? lgu_g[((size_t)j0 * BB + b) * 32 + (t & 31)] : 0.f;
  float err = 0.f, gate = 0.f;

  for (int lj = 0; lj < slen; ++lj) {
    __syncthreads(); // B1
    {
      int dd = t >> 2, cc0 = (t & 3) * 8;
      #pragma unroll
      for (int q = 0; q < 8; ++q) Cl[dd * LDW + cc0 + q] = pf[q];
    }
    if (t < DMD) u_l[t] = un_r;
    const float vld = vld_n;
    const float gu = gu_n;
    // ---- stage A (wave 0): ln(c), logits, shrink, top-8, c update ----
    if (t < 64) {
      const int l = t & 31;
      float cp = c_l[l];
      float mean = redx32(cp) * (1.f / 32.f);
      float dv = cp - mean;
      float vv = redx32(dv * dv) * (1.f / 32.f);
      float cn = dv * rsqrtf(vv + 1e-5f) * cnw_r + cnb_r;
      float logit = lgu_n;
      #pragma unroll 8
      for (int i = 0; i < 32; ++i) logit += __shfl(cn, i) * wcc_l[i * 32 + l];
      float sv = (logit > 0.05f) ? (logit - 0.05f) : ((logit < -0.05f) ? (logit + 0.05f) : 0.f);
      float as = fabsf(sv);
      int rank = 0;
      #pragma unroll 8
      for (int i = 0; i < 32; ++i) {
        float ai = __shfl(as, i);
        rank += (ai > as || (ai == as && i < l)) ? 1 : 0;
      }
      bool sel = rank < 8;
      float av = sel ? sv : 0.f;
      float cnew = 0.9f * cp + 0.1f * av;
      float ct = (vld != 0.f) ? cnew : cp;
      if (t < 32) { a_l[l] = av; c_l[l] = ct; }
      float dp = redx32(ct * wgc_l[l]);
      if (t == 0) dotc_l = dp;
      bool nz = (t < 32) && sel && (av != 0.f);
      unsigned long long bal = __ballot(nz ? 1 : 0);
      if (t < 8) { sel_w[t] = 0.f; sel_i[t] = 0; }
      if (nz) {
        int pos = __popcll(bal & ((1ull << t) - 1ull));
        sel_i[pos] = l; sel_w[pos] = 0.1f * av;
      }
    }
    __syncthreads(); // B2
    // ---- stage B: sparse P update + u_hat/residual ----
    if (vld != 0.f) {
      float accp[8] = {0.f, 0.f, 0.f, 0.f, 0.f, 0.f, 0.f, 0.f};
      float swk[8]; int sik[8];
      #pragma unroll
      for (int kk = 0; kk < 8; ++kk) { swk[kk] = sel_w[kk]; sik[kk] = sel_i[kk]; }
      #pragma unroll
      for (int kk = 0; kk < 8; ++kk) {
        if (swk[kk] != 0.f) {
          const float* rowp = wcdc + (size_t)sik[kk] * 4096;
          #pragma unroll
          for (int m = 0; m < 8; ++m) { int dd = rg + 16 * m; accp[m] += swk[kk] * rowp[dd * 32 + c]; }
        }
      }
      #pragma unroll
      for (int m = 0; m < 8; ++m) { int e = (rg + 16 * m) * LDW + c; Pl[e] = 0.9f * Pl[e] + accp[m]; }
    }
    if (t < DMD) {
      float uh = 0.f;
      #pragma unroll 8
      for (int cc = 0; cc < 32; ++cc) uh += a_l[cc] * Dl[t * LDW + cc];
      float rr = u_l[t] - uh;
      r_l[t] = rr;
      float rp = redx64(rr * rr);
      if ((t & 63) == 0) red[t >> 6] = rp;
    }
    __syncthreads(); // B3
    // ---- stage C: prefetch next; gate; dictionary update ----
    const int ljn = (lj + 1 < slen) ? (lj + 1) : lj;
    const int jn = j0 + ljn;
    load_cand8(cand, ((size_t)ljn * BB + b) * 4096 + (size_t)t * 8, pf);
    if (t < DMD) un_r = chunk_h[((size_t)b * NCH + jn) * DMD + t];
    vld_n = validf[jn * BB + b];
    gu_n = gu_g[jn * BB + b];
    if (t < 64) lgu_n = lgu_g[((size_t)jn * BB + b) * 32 + (t & 31)];
    err = sqrtf(red[0] + red[1]);
    gate = sigmoidf_(gu + dotc_l + err * wge + bgs);
    const float ac = a_l[c];
    float Dv[8], dl[8], dc[8], dn[8];
    float sl = 0.f, sc = 0.f;
    #pragma unroll
    for (int m = 0; m < 8; ++m) {
      int dd = rg + 16 * m; int e = dd * LDW + c;
      Dv[m] = Dl[e];
      dl[m] = Dv[m] + 0.03f * r_l[dd] * ac;
      sl += dl[m] * dl[m];
      dc[m] = Cl[e] + Pl[e];
      sc += dc[m] * dc[m];
    }
    sl = redx16(sl); sc = redx16(sc);
    float il = 1.f / fmaxf(sqrtf(sl), 1e-12f);
    float ic = 1.f / fmaxf(sqrtf(sc), 1e-12f);
    float sn = 0.f;
    #pragma unroll
    for (int m = 0; m < 8; ++m) { dn[m] = (1.f - gate) * dl[m] * il + gate * dc[m] * ic; sn += dn[m] * dn[m]; }
    sn = redx16(sn);
    float inn = 1.f / fmaxf(sqrtf(sn), 1e-12f);
    const bool vb = (vld != 0.f);
    #pragma unroll
    for (int m = 0; m < 8; ++m) {
      int e = (rg + 16 * m) * LDW + c;
      Dl[e] = vb ? dn[m] * inn : Dv[m];
    }
  }
  __syncthreads();
  // ---- persist state ----
  for (int i = t; i < 4096; i += 512) {
    Dst[(size_t)b * 4096 + i] = Dl[(i >> 5) * LDW + (i & 31)];
    Pst[(size_t)b * 4096 + i] = Pl[(i >> 5) * LDW + (i & 31)];
  }
  if (t < CDD) cst[b * CDD + t] = c_l[t];
  if (!doHead) return;
  // ---- head: feat -> LN -> GELU(f1) -> f2 ----
  if (t < DMD) {
    float z = 0.f;
    #pragma unroll 8
    for (int cc = 0; cc < 32; ++cc) z += Dl[t * LDW + cc] * c_l[cc];
    feat[t] = z;
    feat[160 + t] = smean[b * DMD + t];
    feat[288 + t] = smax[b * DMD + t];
  }
  if (t < 32) feat[DMD + t] = c_l[t];
  if (t == 0) { feat[416] = err; feat[417] = gate; }
  __syncthreads();
  float fv = (t < FEATN) ? feat[t] : 0.f;
  float ws1 = redx64(fv);
  if ((t & 63) == 0) red[t >> 6] = ws1;
  __syncthreads();
  float tot = 0.f;
  #pragma unroll
  for (int w = 0; w < 8; ++w) tot += red[w];
  float mean = tot * (1.f / 418.f);
  float dvv = (t < FEATN) ? (fv - mean) : 0.f;
  float ws2 = redx64(dvv * dvv);
  if ((t & 63) == 0) red[8 + (t >> 6)] = ws2;
  __syncthreads();
  float vtot = 0.f;
  #pragma unroll
  for (int w = 0; w < 8; ++w) vtot += red[8 + w];
  float rs = rsqrtf(vtot * (1.f / 418.f) + 1e-5f);
  if (t < FEATN) featn[t] = (fv - mean) * rs * clw[t] + clb[t];
  __syncthreads();
  if (t < 256) {
    float acc = f1b[t];
    for (int f = 0; f < FEATN; ++f) acc += featn[f] * f1w[(size_t)f * 256 + t];
    h1[t] = acc * 0.5f * (1.f + erff(acc * 0.70710678f));
  }
  __syncthreads();
  if (t < 8) {
    float acc = f2b[t];
    #pragma unroll 8
    for (int i = 0; i < 256; ++i) acc += h1[i] * f2w[i * 8 + t];
    out[b * 8 + t] = acc;
  }
}

// ---------------- launch ----------------
extern "C" void kernel_launch(void* const* d_in, const int* in_sizes, int n_in,
                              void* d_out, int out_size, void* d_ws, size_t ws_size,
                              hipStream_t stream) {
  const int*   tokens = (const int*)d_in[0];
  const float* emb    = (const float*)d_in[1];
  const float* in_w   = (const float*)d_in[2];
  const float* in_b   = (const float*)d_in[3];
  const float* c1w    = (const float*)d_in[4];
  const float* c1b    = (const float*)d_in[5];
  const float* c2w    = (const float*)d_in[6];
  const float* c2b    = (const float*)d_in[7];
  const float* op_w   = (const float*)d_in[8];
  const float* op_b   = (const float*)d_in[9];
  const float* on_w   = (const float*)d_in[10];
  const float* on_b   = (const float*)d_in[11];
  const float* base_D = (const float*)d_in[12];
  const float* wcu    = (const float*)d_in[13];
  const float* wcc    = (const float*)d_in[14];
  const float* wcdu   = (const float*)d_in[15];
  const float* bcdu   = (const float*)d_in[16];
  const float* wcdc   = (const float*)d_in[17];
  const float* bcdc   = (const float*)d_in[18];
  const float* wg     = (const float*)d_in[19];
  const float* bg     = (const float*)d_in[20];
  const float* un_w   = (const float*)d_in[21];
  const float* un_b   = (const float*)d_in[22];
  const float* cn_w   = (const float*)d_in[23];
  const float* cn_b   = (const float*)d_in[24];
  const float* cl_w   = (const float*)d_in[25];
  const float* cl_b   = (const float*)d_in[26];
  const float* f1w    = (const float*)d_in[27];
  const float* f1b    = (const float*)d_in[28];
  const float* f2w    = (const float*)d_in[29];
  const float* f2b    = (const float*)d_in[30];

  // ---- adaptive workspace layout ----
  const size_t FIXED_BYTES = 27615232ull;     // all f32 arrays below
  const size_t SEG_UNIT = (size_t)BB * 4096 * 2;  // 512 KB per step (bf16)
  int S = 512;
  while (S > 1 && (size_t)S * SEG_UNIT + FIXED_BYTES > ws_size) S >>= 1;

  unsigned short* cand = (unsigned short*)d_ws;
  float* base = (float*)((char*)d_ws + (size_t)S * SEG_UNIT);
  float* chunk_h = base; base += (size_t)BB * NCH * DMD;   // 4,194,304
  float* validf  = base; base += (size_t)NCH * BB;         // 32,768
  float* lgu     = base; base += (size_t)NCH * BB * 32;    // 1,048,576
  float* gu      = base; base += (size_t)NCH * BB;         // 32,768
  float* spsum   = base; base += (size_t)BB * 64 * DMD;    // 524,288
  float* spmax   = base; base += (size_t)BB * 64 * DMD;    // 524,288
  float* spcnt   = base; base += (size_t)BB * 64;          // 4,096
  float* smean   = base; base += (size_t)BB * DMD;         // 8,192
  float* smaxv   = base; base += (size_t)BB * DMD;         // 8,192
  float* Dst     = base; base += (size_t)BB * 4096;        // 262,144
  float* Pst     = base; base += (size_t)BB * 4096;        // 262,144
  float* cst     = base; base += (size_t)BB * CDD;         // 2,048
  float* out = (float*)d_out;
  fprintf(stderr, "[hsfc69] ws_size=%zu fixed=%zu S=%d total=%zu\n",
          ws_size, FIXED_BYTES, S, FIXED_BYTES + (size_t)S * SEG_UNIT);

  k_front<<<dim3(64, BB), dim3(256), 0, stream>>>(
      tokens, emb, in_w, in_b, c1w, c1b, c2w, c2b, op_w, op_b, on_w, on_b,
      un_w, un_b, wcu, wg, chunk_h, validf, lgu, gu, spsum, spmax, spcnt);
  k_surface<<<dim3(BB), dim3(128), 0, stream>>>(spsum, spmax, spcnt, smean, smaxv);
  for (int j0 = 0; j0 < NCH; j0 += S) {
    k_cand<<<dim3(32, S), dim3(256), 0, stream>>>(chunk_h, wcdu, bcdu, bcdc, cand, j0);
    k_scan_seg<<<dim3(BB), dim3(512), 0, stream>>>(
        chunk_h, lgu, gu, validf, cand, j0, S,
        wcc, wcdc, wg, bg, cn_w, cn_b, base_D, Dst, Pst, cst,
        smean, smaxv, cl_w, cl_b, f1w, f1b, f2w, f2b, out);
  }
}

// Round 3
// 4144.740 us; speedup vs baseline: 2.8416x; 2.8416x over previous
//
#include <hip/hip_runtime.h>
#include <hip/hip_bf16.h>
#include <cfloat>
#include <cstdio>

#define TT   2048
#define BB   64
#define DMD  128
#define CDD  32
#define NCH  512
#define FEATN 418
#define LDW  33     // padded leading dim for 128x32 LDS tiles in scan
#define APITCH 130  // front A-tile pitch
#define YPITCH 257  // front Y-tile pitch
#define CPITCH 164  // cand A-tile pitch (K=160)

// ---------------- helpers ----------------
__device__ __forceinline__ float redx16(float v) {
  v += __shfl_xor(v, 1); v += __shfl_xor(v, 2);
  v += __shfl_xor(v, 4); v += __shfl_xor(v, 8);
  return v;
}
__device__ __forceinline__ float redx32(float v) { v = redx16(v); v += __shfl_xor(v, 16); return v; }
__device__ __forceinline__ float redx64(float v) { v = redx32(v); v += __shfl_xor(v, 32); return v; }
__device__ __forceinline__ float bfbits2f(unsigned int u) {
  union { unsigned int i; float f; } v; v.i = u << 16; return v.f;
}
__device__ __forceinline__ unsigned short f2bf(float f) {
  union { float f; unsigned int i; } u; u.f = f;
  unsigned int r = u.i + 0x7FFFu + ((u.i >> 16) & 1u);
  return (unsigned short)(r >> 16);
}
__device__ __forceinline__ float sigmoidf_(float x) { return 1.f / (1.f + expf(-x)); }

__device__ __forceinline__ void load_cand8(const unsigned short* cand, size_t idx, float* pf) {
  uint4 v = *reinterpret_cast<const uint4*>(cand + idx);
  pf[0] = bfbits2f(v.x & 0xFFFFu); pf[1] = bfbits2f(v.x >> 16);
  pf[2] = bfbits2f(v.y & 0xFFFFu); pf[3] = bfbits2f(v.y >> 16);
  pf[4] = bfbits2f(v.z & 0xFFFFu); pf[5] = bfbits2f(v.z >> 16);
  pf[6] = bfbits2f(v.w & 0xFFFFu); pf[7] = bfbits2f(v.w >> 16);
}

// ============================================================================
// k_front: per 32-position tile: embed+LN -> conv3/5+GLU -> op+residual+LN ->
// chunk means, validity, surface partials, ln(u)@wcu, u@wg.
// ============================================================================
__global__ __launch_bounds__(256) void k_front(
    const int* __restrict__ tokens, const float* __restrict__ emb,
    const float* __restrict__ inw, const float* __restrict__ inb,
    const float* __restrict__ c1w, const float* __restrict__ c1b,
    const float* __restrict__ c2w, const float* __restrict__ c2b,
    const float* __restrict__ opw, const float* __restrict__ opb,
    const float* __restrict__ onw, const float* __restrict__ onb,
    const float* __restrict__ unw, const float* __restrict__ unb,
    const float* __restrict__ wcu, const float* __restrict__ wgv,
    float* __restrict__ chunk_h, float* __restrict__ validf,
    float* __restrict__ lgu, float* __restrict__ gu,
    float* __restrict__ spsum, float* __restrict__ spmax, float* __restrict__ spcnt) {
  __shared__ float A[36 * APITCH];   // x tile rows t0-2..t0+33
  __shared__ float Y[32 * YPITCH];   // y12 tile; later reused for partials/lnu
  __shared__ float Wl[2048];         // weight staging
  __shared__ float tokm[32];
  const int b = blockIdx.y, tile = blockIdx.x;
  const int t0 = tile * 32;
  const int t = threadIdx.x;
  const int lane = t & 63, wv = t >> 6;

  // ---- phase 0: embed + input LN into A (zero pad outside sequence) ----
  for (int r = wv; r < 36; r += 4) {
    int p = t0 + r - 2;
    float2 o = make_float2(0.f, 0.f);
    if (p >= 0 && p < TT) {
      int tok = tokens[b * TT + p];
      if (lane == 0 && r >= 2 && r < 34) tokm[r - 2] = (tok != 0) ? 1.f : 0.f;
      float2 e = *reinterpret_cast<const float2*>(emb + (size_t)tok * DMD + lane * 2);
      float mean = redx64(e.x + e.y) * (1.f / 128.f);
      float d0 = e.x - mean, d1 = e.y - mean;
      float vvv = redx64(d0 * d0 + d1 * d1) * (1.f / 128.f);
      float rs = rsqrtf(vvv + 1e-5f);
      o.x = d0 * rs * inw[lane * 2]     + inb[lane * 2];
      o.y = d1 * rs * inw[lane * 2 + 1] + inb[lane * 2 + 1];
    }
    *reinterpret_cast<float2*>(&A[r * APITCH + lane * 2]) = o;
  }
  const int tm = t >> 4, tn = t & 15;
  const int r0 = tm * 2;
  float acc[2][16];

  // ---- phase 1a: conv3 + GLU -> Y cols 0..127 ----
  #pragma unroll
  for (int m = 0; m < 2; ++m)
    #pragma unroll
    for (int q = 0; q < 16; ++q) acc[m][q] = 0.f;
  for (int k0 = 0; k0 < 384; k0 += 8) {
    __syncthreads();
    {
      int kk = t >> 5, oo = (t & 31) * 8;
      *reinterpret_cast<float4*>(&Wl[kk * 256 + oo])     = *reinterpret_cast<const float4*>(&c1w[(size_t)(k0 + kk) * 256 + oo]);
      *reinterpret_cast<float4*>(&Wl[kk * 256 + oo + 4]) = *reinterpret_cast<const float4*>(&c1w[(size_t)(k0 + kk) * 256 + oo + 4]);
    }
    __syncthreads();
    #pragma unroll
    for (int kk = 0; kk < 8; ++kk) {
      int k = k0 + kk, tap = k >> 7, ii = k & 127;
      float a0 = A[(r0 + tap + 1) * APITCH + ii];
      float a1 = A[(r0 + tap + 2) * APITCH + ii];
      float w16[16];
      *reinterpret_cast<float4*>(&w16[0])  = *reinterpret_cast<float4*>(&Wl[kk * 256 + tn * 8]);
      *reinterpret_cast<float4*>(&w16[4])  = *reinterpret_cast<float4*>(&Wl[kk * 256 + tn * 8 + 4]);
      *reinterpret_cast<float4*>(&w16[8])  = *reinterpret_cast<float4*>(&Wl[kk * 256 + 128 + tn * 8]);
      *reinterpret_cast<float4*>(&w16[12]) = *reinterpret_cast<float4*>(&Wl[kk * 256 + 128 + tn * 8 + 4]);
      #pragma unroll
      for (int q = 0; q < 16; ++q) { acc[0][q] += a0 * w16[q]; acc[1][q] += a1 * w16[q]; }
    }
  }
  #pragma unroll
  for (int m = 0; m < 2; ++m)
    #pragma unroll
    for (int q = 0; q < 8; ++q) {
      float av = acc[m][q]     + c1b[tn * 8 + q];
      float gv = acc[m][q + 8] + c1b[128 + tn * 8 + q];
      Y[(r0 + m) * YPITCH + tn * 8 + q] = av * sigmoidf_(gv);
    }

  // ---- phase 1b: conv5 + GLU -> Y cols 128..255 ----
  #pragma unroll
  for (int m = 0; m < 2; ++m)
    #pragma unroll
    for (int q = 0; q < 16; ++q) acc[m][q] = 0.f;
  for (int k0 = 0; k0 < 640; k0 += 8) {
    __syncthreads();
    {
      int kk = t >> 5, oo = (t & 31) * 8;
      *reinterpret_cast<float4*>(&Wl[kk * 256 + oo])     = *reinterpret_cast<const float4*>(&c2w[(size_t)(k0 + kk) * 256 + oo]);
      *reinterpret_cast<float4*>(&Wl[kk * 256 + oo + 4]) = *reinterpret_cast<const float4*>(&c2w[(size_t)(k0 + kk) * 256 + oo + 4]);
    }
    __syncthreads();
    #pragma unroll
    for (int kk = 0; kk < 8; ++kk) {
      int k = k0 + kk, tap = k >> 7, ii = k & 127;
      float a0 = A[(r0 + tap) * APITCH + ii];
      float a1 = A[(r0 + tap + 1) * APITCH + ii];
      float w16[16];
      *reinterpret_cast<float4*>(&w16[0])  = *reinterpret_cast<float4*>(&Wl[kk * 256 + tn * 8]);
      *reinterpret_cast<float4*>(&w16[4])  = *reinterpret_cast<float4*>(&Wl[kk * 256 + tn * 8 + 4]);
      *reinterpret_cast<float4*>(&w16[8])  = *reinterpret_cast<float4*>(&Wl[kk * 256 + 128 + tn * 8]);
      *reinterpret_cast<float4*>(&w16[12]) = *reinterpret_cast<float4*>(&Wl[kk * 256 + 128 + tn * 8 + 4]);
      #pragma unroll
      for (int q = 0; q < 16; ++q) { acc[0][q] += a0 * w16[q]; acc[1][q] += a1 * w16[q]; }
    }
  }
  #pragma unroll
  for (int m = 0; m < 2; ++m)
    #pragma unroll
    for (int q = 0; q < 8; ++q) {
      float av = acc[m][q]     + c2b[tn * 8 + q];
      float gv = acc[m][q + 8] + c2b[128 + tn * 8 + q];
      Y[(r0 + m) * YPITCH + 128 + tn * 8 + q] = av * sigmoidf_(gv);
    }

  // ---- phase 2: op GEMM (Y @ op_w) + residual + LN -> h (registers) ----
  float acc2[2][8] = {};
  for (int k0 = 0; k0 < 256; k0 += 16) {
    __syncthreads();
    {
      int kc = t >> 4, oo = (t & 15) * 8;
      *reinterpret_cast<float4*>(&Wl[kc * 128 + oo])     = *reinterpret_cast<const float4*>(&opw[(size_t)(k0 + kc) * 128 + oo]);
      *reinterpret_cast<float4*>(&Wl[kc * 128 + oo + 4]) = *reinterpret_cast<const float4*>(&opw[(size_t)(k0 + kc) * 128 + oo + 4]);
    }
    __syncthreads();
    #pragma unroll
    for (int kc = 0; kc < 16; ++kc) {
      int k = k0 + kc;
      float y0 = Y[r0 * YPITCH + k];
      float y1 = Y[(r0 + 1) * YPITCH + k];
      float w8[8];
      *reinterpret_cast<float4*>(&w8[0]) = *reinterpret_cast<float4*>(&Wl[kc * 128 + tn * 8]);
      *reinterpret_cast<float4*>(&w8[4]) = *reinterpret_cast<float4*>(&Wl[kc * 128 + tn * 8 + 4]);
      #pragma unroll
      for (int q = 0; q < 8; ++q) { acc2[0][q] += y0 * w8[q]; acc2[1][q] += y1 * w8[q]; }
    }
  }
  __syncthreads();  // all Y reads complete; Y region reusable

  const int col = tn * 8;
  float hreg[2][8];
  float msk[2];
  #pragma unroll
  for (int m = 0; m < 2; ++m) {
    int row = r0 + m;
    float vals[8]; float s = 0.f;
    const float* xr = &A[(row + 2) * APITCH + col];
    #pragma unroll
    for (int q = 0; q < 8; ++q) { vals[q] = acc2[m][q] + opb[col + q] + xr[q]; s += vals[q]; }
    s = redx16(s);
    float mean = s * (1.f / 128.f);
    float vv2 = 0.f;
    #pragma unroll
    for (int q = 0; q < 8; ++q) { float d = vals[q] - mean; vv2 += d * d; }
    vv2 = redx16(vv2) * (1.f / 128.f);
    float rs = rsqrtf(vv2 + 1e-5f);
    #pragma unroll
    for (int q = 0; q < 8; ++q) hreg[m][q] = (vals[q] - mean) * rs * onw[col + q] + onb[col + q];
    msk[m] = tokm[row];
  }

  // ---- phase 3: surface partials + chunk means + lgu/gu ----
  float* partS = Y;               // 16*128
  float* partM = Y + 2048;        // 16*128
  float* lnus  = Y + 4096;        // 8*128
  float ps[8], pm[8];
  #pragma unroll
  for (int q = 0; q < 8; ++q) {
    ps[q] = msk[0] * hreg[0][q] + msk[1] * hreg[1][q];
    float m0 = (msk[0] != 0.f) ? hreg[0][q] : -FLT_MAX;
    float m1 = (msk[1] != 0.f) ? hreg[1][q] : -FLT_MAX;
    pm[q] = fmaxf(m0, m1);
  }
  #pragma unroll
  for (int q = 0; q < 8; ++q) { partS[tm * 128 + col + q] = ps[q]; partM[tm * 128 + col + q] = pm[q]; }

  float ccnt = msk[0] + msk[1];
  float csum[8];
  #pragma unroll
  for (int q = 0; q < 8; ++q) csum[q] = ps[q];
  #pragma unroll
  for (int q = 0; q < 8; ++q) csum[q] += __shfl_xor(csum[q], 16);
  ccnt += __shfl_xor(ccnt, 16);

  if ((tm & 1) == 0) {
    int jg = tile * 8 + (tm >> 1);
    float inv = 1.f / fmaxf(ccnt, 1.f);
    float cm[8];
    #pragma unroll
    for (int q = 0; q < 8; ++q) cm[q] = csum[q] * inv;
    *reinterpret_cast<float4*>(&chunk_h[((size_t)b * NCH + jg) * DMD + col])     = *reinterpret_cast<float4*>(&cm[0]);
    *reinterpret_cast<float4*>(&chunk_h[((size_t)b * NCH + jg) * DMD + col + 4]) = *reinterpret_cast<float4*>(&cm[4]);
    if (tn == 0) validf[jg * BB + b] = (ccnt > 0.f) ? 1.f : 0.f;
    float gp = 0.f;
    #pragma unroll
    for (int q = 0; q < 8; ++q) gp += cm[q] * wgv[col + q];
    gp = redx16(gp);
    if (tn == 0) gu[(size_t)jg * BB + b] = gp;
    float s2 = 0.f;
    #pragma unroll
    for (int q = 0; q < 8; ++q) s2 += cm[q];
    s2 = redx16(s2);
    float mean2 = s2 * (1.f / 128.f);
    float v3 = 0.f;
    #pragma unroll
    for (int q = 0; q < 8; ++q) { float d = cm[q] - mean2; v3 += d * d; }
    v3 = redx16(v3) * (1.f / 128.f);
    float rs2 = rsqrtf(v3 + 1e-5f);
    int ch = tm >> 1;
    #pragma unroll
    for (int q = 0; q < 8; ++q) lnus[ch * 128 + col + q] = (cm[q] - mean2) * rs2 * unw[col + q] + unb[col + q];
  }
  __syncthreads();
  // lgu: 8 chunks x 32 outputs
  {
    int ch = t >> 5, o = t & 31;
    float accl = 0.f;
    for (int d = 0; d < 128; ++d) accl += lnus[ch * 128 + d] * wcu[d * 32 + o];
    int jg2 = tile * 8 + ch;
    lgu[((size_t)jg2 * BB + b) * 32 + o] = accl;
  }
  if (t < 128) {
    float s3 = 0.f, m3 = -FLT_MAX;
    #pragma unroll
    for (int g = 0; g < 16; ++g) { s3 += partS[g * 128 + t]; m3 = fmaxf(m3, partM[g * 128 + t]); }
    spsum[((size_t)b * 64 + tile) * DMD + t] = s3;
    spmax[((size_t)b * 64 + tile) * DMD + t] = m3;
  }
  if (t == 128) {
    float cnt = 0.f;
    for (int r = 0; r < 32; ++r) cnt += tokm[r];
    spcnt[b * 64 + tile] = cnt;
  }
}

// ---------------- surface finalize ----------------
__global__ __launch_bounds__(128) void k_surface(
    const float* __restrict__ spsum, const float* __restrict__ spmax, const float* __restrict__ spcnt,
    float* __restrict__ smean, float* __restrict__ smax) {
  const int b = blockIdx.x, d = threadIdx.x;
  float s = 0.f, m = -FLT_MAX, cnt = 0.f;
  for (int p = 0; p < 64; ++p) {
    s += spsum[((size_t)b * 64 + p) * DMD + d];
    m = fmaxf(m, spmax[((size_t)b * 64 + p) * DMD + d]);
    cnt += spcnt[b * 64 + p];
  }
  smean[b * DMD + d] = s / fmaxf(cnt, 1.f);
  smax[b * DMD + d] = (cnt > 0.f) ? m : 0.f;
}

// ============================================================================
// k_accrec: the closed (a, c) recurrence for all 512 steps.
// One wave per batch (both 32-halves duplicate compute); no block barriers
// in the loop. Emits a_j, c_j, gpart_j = gu + c_t@wgc + bg for every step.
// ============================================================================
__global__ __launch_bounds__(256) void k_accrec(
    const float* __restrict__ lgu, const float* __restrict__ gu,
    const float* __restrict__ validf,
    const float* __restrict__ wcc, const float* __restrict__ cnw, const float* __restrict__ cnb,
    const float* __restrict__ wg, const float* __restrict__ bg,
    float* __restrict__ a_g, float* __restrict__ c_g, float* __restrict__ gpart_g) {
  __shared__ float wcc_l[CDD * CDD];
  __shared__ float cn_s[4][CDD];
  __shared__ float as_s[4][CDD];
  const int t = threadIdx.x;
  const int w = t >> 6, lane = t & 63, l = lane & 31;
  const int b = blockIdx.x * 4 + w;
  for (int i = t; i < CDD * CDD; i += 256) wcc_l[i] = wcc[i];
  __syncthreads();
  const float cw = cnw[l], cb = cnb[l], wgc = wg[DMD + l];
  const float bgs = bg[0];
  float c = 0.f;
  for (int j = 0; j < NCH; ++j) {
    const size_t jb = (size_t)j * BB + b;
    float lg = lgu[jb * 32 + l];
    float vld = validf[jb];
    float guv = gu[jb];
    // ln(c) over 32 dims (within each 32-lane half)
    float mean = redx32(c) * (1.f / 32.f);
    float dv = c - mean;
    float var = redx32(dv * dv) * (1.f / 32.f);
    float cn = dv * rsqrtf(var + 1e-5f) * cw + cb;
    if (lane < 32) cn_s[w][l] = cn;
    // logits = lgu + cn @ wcc (two independent accumulation chains)
    float l0 = lg, l1 = 0.f;
    #pragma unroll
    for (int i = 0; i < 16; ++i) {
      l0 += cn_s[w][i] * wcc_l[i * 32 + l];
      l1 += cn_s[w][i + 16] * wcc_l[(i + 16) * 32 + l];
    }
    float logit = l0 + l1;
    float sv = (logit > 0.05f) ? (logit - 0.05f) : ((logit < -0.05f) ? (logit + 0.05f) : 0.f);
    float as = fabsf(sv);
    if (lane < 32) as_s[w][l] = as;
    int r0 = 0, r1 = 0;
    #pragma unroll
    for (int i = 0; i < 16; ++i) {
      float a0 = as_s[w][i], a1 = as_s[w][i + 16];
      r0 += (a0 > as || (a0 == as && i < l)) ? 1 : 0;
      r1 += (a1 > as || (a1 == as && (i + 16) < l)) ? 1 : 0;
    }
    float av = ((r0 + r1) < 8) ? sv : 0.f;
    float ct = (vld != 0.f) ? (0.9f * c + 0.1f * av) : c;
    c = ct;
    float dotc = redx32(ct * wgc);
    if (lane < 32) {
      a_g[jb * 32 + l] = av;
      c_g[jb * 32 + l] = ct;
      if (l == 0) gpart_g[jb] = guv + dotc + bgs;
    }
  }
}

// ---------------- cand_total = [u|c_t] @ [wcdu;wcdc] + (bcdu+bcdc), bf16 ----
__global__ __launch_bounds__(256) void k_cand(
    const float* __restrict__ chunk_h, const float* __restrict__ c_g,
    const float* __restrict__ wcdu, const float* __restrict__ wcdc,
    const float* __restrict__ bcdu, const float* __restrict__ bcdc,
    unsigned short* __restrict__ cand, int j0) {
  __shared__ float A[64 * CPITCH];
  __shared__ float Wl[16 * 128];
  const int lj = blockIdx.y;
  const int j = j0 + lj;
  const int n0 = blockIdx.x * 128;
  {
    int m = threadIdx.x >> 2, ks = (threadIdx.x & 3) * 32;
    const float* src = chunk_h + ((size_t)m * NCH + j) * DMD + ks;
    #pragma unroll
    for (int q = 0; q < 32; q += 4)
      *reinterpret_cast<float4*>(&A[m * CPITCH + ks + q]) = *reinterpret_cast<const float4*>(&src[q]);
    int kc0 = (threadIdx.x & 3) * 8;
    const float* csrc = c_g + ((size_t)j * BB + m) * 32 + kc0;
    *reinterpret_cast<float4*>(&A[m * CPITCH + 128 + kc0])     = *reinterpret_cast<const float4*>(&csrc[0]);
    *reinterpret_cast<float4*>(&A[m * CPITCH + 128 + kc0 + 4]) = *reinterpret_cast<const float4*>(&csrc[4]);
  }
  const int tm = threadIdx.x >> 4, tn = threadIdx.x & 15;
  float acc[4][8] = {};
  for (int k0 = 0; k0 < 160; k0 += 16) {
    __syncthreads();
    {
      int kc = threadIdx.x >> 4, oo = (threadIdx.x & 15) * 8;
      int kr = k0 + kc;
      const float* wsrc = (kr < 128) ? &wcdu[(size_t)kr * 4096 + n0] : &wcdc[(size_t)(kr - 128) * 4096 + n0];
      *reinterpret_cast<float4*>(&Wl[kc * 128 + oo])     = *reinterpret_cast<const float4*>(&wsrc[oo]);
      *reinterpret_cast<float4*>(&Wl[kc * 128 + oo + 4]) = *reinterpret_cast<const float4*>(&wsrc[oo + 4]);
    }
    __syncthreads();
    #pragma unroll
    for (int kc = 0; kc < 16; ++kc) {
      int k = k0 + kc;
      float a0 = A[(tm * 4 + 0) * CPITCH + k];
      float a1 = A[(tm * 4 + 1) * CPITCH + k];
      float a2 = A[(tm * 4 + 2) * CPITCH + k];
      float a3 = A[(tm * 4 + 3) * CPITCH + k];
      float w8[8];
      *reinterpret_cast<float4*>(&w8[0]) = *reinterpret_cast<float4*>(&Wl[kc * 128 + tn * 8]);
      *reinterpret_cast<float4*>(&w8[4]) = *reinterpret_cast<float4*>(&Wl[kc * 128 + tn * 8 + 4]);
      #pragma unroll
      for (int q = 0; q < 8; ++q) {
        acc[0][q] += a0 * w8[q]; acc[1][q] += a1 * w8[q];
        acc[2][q] += a2 * w8[q]; acc[3][q] += a3 * w8[q];
      }
    }
  }
  const int colb = n0 + tn * 8;
  float bsum[8];
  #pragma unroll
  for (int q = 0; q < 8; ++q) bsum[q] = bcdu[colb + q] + bcdc[colb + q];
  #pragma unroll
  for (int r = 0; r < 4; ++r) {
    int bb2 = tm * 4 + r;
    size_t o = ((size_t)lj * BB + bb2) * 4096 + colb;
    unsigned short tmp[8];
    #pragma unroll
    for (int q = 0; q < 8; ++q) tmp[q] = f2bf(acc[r][q] + bsum[q]);
    uint4 pk;
    pk.x = (unsigned int)tmp[0] | ((unsigned int)tmp[1] << 16);
    pk.y = (unsigned int)tmp[2] | ((unsigned int)tmp[3] << 16);
    pk.z = (unsigned int)tmp[4] | ((unsigned int)tmp[5] << 16);
    pk.w = (unsigned int)tmp[6] | ((unsigned int)tmp[7] << 16);
    *reinterpret_cast<uint4*>(&cand[o]) = pk;
  }
}

// ============================================================================
// k_scan_seg: D-only recurrence, 2 barriers/step, D in registers (Dv[8]),
// no unprefetchable global traffic. One block per batch.
// ============================================================================
__global__ __launch_bounds__(512) void k_scan_seg(
    const float* __restrict__ chunk_h, const float* __restrict__ a_gg,
    const float* __restrict__ c_g, const float* __restrict__ gpart_g,
    const float* __restrict__ validf,
    const unsigned short* __restrict__ cand, int j0, int slen,
    const float* __restrict__ wg, const float* __restrict__ base_D,
    float* __restrict__ Dst,
    const float* __restrict__ smean, const float* __restrict__ smax,
    const float* __restrict__ clw, const float* __restrict__ clb,
    const float* __restrict__ f1w, const float* __restrict__ f1b,
    const float* __restrict__ f2w, const float* __restrict__ f2b,
    float* __restrict__ out) {
  __shared__ float Dl[DMD * LDW];
  __shared__ float Cl[DMD * LDW];
  __shared__ float a_l[CDD];
  __shared__ float r_l[DMD];
  __shared__ float red[8];
  __shared__ float feat[FEATN + 2];
  __shared__ float featn[FEATN + 2];
  __shared__ float h1[256];

  const int b = blockIdx.x;
  const int t = threadIdx.x;
  const int c = t >> 4;     // column 0..31
  const int rg = t & 15;    // rows rg+16m, m<8
  const bool doInit = (j0 == 0);
  const bool doHead = (j0 + slen >= NCH);
  const float wge = wg[160];

  if (doInit) {
    for (int i = t; i < DMD * CDD; i += 512) Dl[(i >> 5) * LDW + (i & 31)] = base_D[i];
  } else {
    for (int i = t; i < DMD * CDD; i += 512) Dl[(i >> 5) * LDW + (i & 31)] = Dst[(size_t)b * 4096 + i];
  }
  __syncthreads();
  float Dv[8];
  if (doInit) {
    float s = 0.f;
    #pragma unroll
    for (int m = 0; m < 8; ++m) { Dv[m] = Dl[(rg + 16 * m) * LDW + c]; s += Dv[m] * Dv[m]; }
    s = redx16(s);
    float inv = 1.f / fmaxf(sqrtf(s), 1e-12f);
    #pragma unroll
    for (int m = 0; m < 8; ++m) { Dv[m] *= inv; Dl[(rg + 16 * m) * LDW + c] = Dv[m]; }
  } else {
    #pragma unroll
    for (int m = 0; m < 8; ++m) Dv[m] = Dl[(rg + 16 * m) * LDW + c];
  }
  // prologue prefetch for first step
  float pf[8];
  load_cand8(cand, ((size_t)0 * BB + b) * 4096 + (size_t)t * 8, pf);
  float un_r = (t < DMD) ? chunk_h[((size_t)b * NCH + j0) * DMD + t] : 0.f;
  float a_col = a_gg[((size_t)j0 * BB + b) * 32 + c];
  if (t < 32) a_l[t] = a_gg[((size_t)j0 * BB + b) * 32 + t];
  float gpart = gpart_g[(size_t)j0 * BB + b];
  float vld = validf[(size_t)j0 * BB + b];
  float err = 0.f, gate = 0.f;

  for (int lj = 0; lj < slen; ++lj) {
    __syncthreads(); // B1: prev Dl writes + a_l visible; Cl free
    {
      int dd = t >> 2, cc0 = (t & 3) * 8;
      #pragma unroll
      for (int q = 0; q < 8; ++q) Cl[dd * LDW + cc0 + q] = pf[q];
    }
    if (t < DMD) {
      float uh = 0.f;
      #pragma unroll
      for (int cc = 0; cc < 32; ++cc) uh += a_l[cc] * Dl[t * LDW + cc];
      float rr = un_r - uh;
      r_l[t] = rr;
      float rp = redx64(rr * rr);
      if ((t & 63) == 0) red[t >> 6] = rp;
    }
    __syncthreads(); // B2: r_l, red, Cl visible
    err = sqrtf(red[0] + red[1]);
    gate = sigmoidf_(gpart + err * wge);
    // prefetch next step (drains at next B1, covered by D-update below)
    const int ljn = (lj + 1 < slen) ? (lj + 1) : lj;
    const int jn = j0 + ljn;
    float pfN[8];
    load_cand8(cand, ((size_t)ljn * BB + b) * 4096 + (size_t)t * 8, pfN);
    float unN = (t < DMD) ? chunk_h[((size_t)b * NCH + jn) * DMD + t] : 0.f;
    float aColN = a_gg[((size_t)jn * BB + b) * 32 + c];
    float a32N = (t < 32) ? a_gg[((size_t)jn * BB + b) * 32 + t] : 0.f;
    float gpN = gpart_g[(size_t)jn * BB + b];
    float vldN = validf[(size_t)jn * BB + b];
    // D update
    float dl[8], dcv[8], dn[8];
    float sl = 0.f, sc = 0.f;
    #pragma unroll
    for (int m = 0; m < 8; ++m) {
      int e = (rg + 16 * m) * LDW + c;
      dl[m] = Dv[m] + 0.03f * r_l[rg + 16 * m] * a_col;
      sl += dl[m] * dl[m];
      dcv[m] = Cl[e];
      sc += dcv[m] * dcv[m];
    }
    sl = redx16(sl); sc = redx16(sc);
    float il = 1.f / fmaxf(sqrtf(sl), 1e-12f);
    float ic = 1.f / fmaxf(sqrtf(sc), 1e-12f);
    float g1 = 1.f - gate;
    float sn = 0.f;
    #pragma unroll
    for (int m = 0; m < 8; ++m) { dn[m] = g1 * dl[m] * il + gate * dcv[m] * ic; sn += dn[m] * dn[m]; }
    sn = redx16(sn);
    float inn = 1.f / fmaxf(sqrtf(sn), 1e-12f);
    const bool vb = (vld != 0.f);
    #pragma unroll
    for (int m = 0; m < 8; ++m) {
      if (vb) Dv[m] = dn[m] * inn;
      Dl[(rg + 16 * m) * LDW + c] = Dv[m];
    }
    if (t < 32) a_l[t] = a32N;   // safe: all a_l reads for this step ended at B2
    #pragma unroll
    for (int q = 0; q < 8; ++q) pf[q] = pfN[q];
    un_r = unN; a_col = aColN; gpart = gpN; vld = vldN;
  }
  __syncthreads();
  for (int i = t; i < 4096; i += 512) Dst[(size_t)b * 4096 + i] = Dl[(i >> 5) * LDW + (i & 31)];
  if (!doHead) return;
  // ---- head: feat -> LN -> GELU(f1) -> f2 ----
  if (t < 32) a_l[t] = c_g[((size_t)(NCH - 1) * BB + b) * 32 + t];  // c_last
  __syncthreads();
  if (t < DMD) {
    float z = 0.f;
    #pragma unroll
    for (int cc = 0; cc < 32; ++cc) z += Dl[t * LDW + cc] * a_l[cc];
    feat[t] = z;
    feat[160 + t] = smean[b * DMD + t];
    feat[288 + t] = smax[b * DMD + t];
  }
  if (t >= 128 && t < 160) feat[t] = a_l[t - 128];
  if (t == 0) { feat[416] = err; feat[417] = gate; }
  __syncthreads();
  float fv = (t < FEATN) ? feat[t] : 0.f;
  float ws1 = redx64(fv);
  if ((t & 63) == 0) red[t >> 6] = ws1;
  __syncthreads();
  float tot = 0.f;
  #pragma unroll
  for (int w = 0; w < 8; ++w) tot += red[w];
  float mean = tot * (1.f / 418.f);
  float dvv = (t < FEATN) ? (fv - mean) : 0.f;
  float ws2 = redx64(dvv * dvv);
  __syncthreads();
  if ((t & 63) == 0) red[t >> 6] = ws2;
  __syncthreads();
  float vtot = 0.f;
  #pragma unroll
  for (int w = 0; w < 8; ++w) vtot += red[w];
  float rs = rsqrtf(vtot * (1.f / 418.f) + 1e-5f);
  if (t < FEATN) featn[t] = (fv - mean) * rs * clw[t] + clb[t];
  __syncthreads();
  if (t < 256) {
    float acc = f1b[t];
    for (int f = 0; f < FEATN; ++f) acc += featn[f] * f1w[(size_t)f * 256 + t];
    h1[t] = acc * 0.5f * (1.f + erff(acc * 0.70710678f));
  }
  __syncthreads();
  if (t < 8) {
    float acc = f2b[t];
    #pragma unroll 8
    for (int i = 0; i < 256; ++i) acc += h1[i] * f2w[i * 8 + t];
    out[b * 8 + t] = acc;
  }
}

// ---------------- launch ----------------
extern "C" void kernel_launch(void* const* d_in, const int* in_sizes, int n_in,
                              void* d_out, int out_size, void* d_ws, size_t ws_size,
                              hipStream_t stream) {
  const int*   tokens = (const int*)d_in[0];
  const float* emb    = (const float*)d_in[1];
  const float* in_w   = (const float*)d_in[2];
  const float* in_b   = (const float*)d_in[3];
  const float* c1w    = (const float*)d_in[4];
  const float* c1b    = (const float*)d_in[5];
  const float* c2w    = (const float*)d_in[6];
  const float* c2b    = (const float*)d_in[7];
  const float* op_w   = (const float*)d_in[8];
  const float* op_b   = (const float*)d_in[9];
  const float* on_w   = (const float*)d_in[10];
  const float* on_b   = (const float*)d_in[11];
  const float* base_D = (const float*)d_in[12];
  const float* wcu    = (const float*)d_in[13];
  const float* wcc    = (const float*)d_in[14];
  const float* wcdu   = (const float*)d_in[15];
  const float* bcdu   = (const float*)d_in[16];
  const float* wcdc   = (const float*)d_in[17];
  const float* bcdc   = (const float*)d_in[18];
  const float* wg     = (const float*)d_in[19];
  const float* bg     = (const float*)d_in[20];
  const float* un_w   = (const float*)d_in[21];
  const float* un_b   = (const float*)d_in[22];
  const float* cn_w   = (const float*)d_in[23];
  const float* cn_b   = (const float*)d_in[24];
  const float* cl_w   = (const float*)d_in[25];
  const float* cl_b   = (const float*)d_in[26];
  const float* f1w    = (const float*)d_in[27];
  const float* f1b    = (const float*)d_in[28];
  const float* f2w    = (const float*)d_in[29];
  const float* f2b    = (const float*)d_in[30];

  // ---- adaptive workspace layout ----
  const size_t CHEL = (size_t)BB * NCH * DMD;          // 4,194,304
  const size_t NB   = (size_t)NCH * BB;                // 32,768
  size_t fixedFloats = CHEL + NB /*validf*/ + NB * 32 /*lgu*/ + NB /*gu*/
                     + (size_t)BB * 64 * DMD * 2 /*spsum+spmax*/ + (size_t)BB * 64 /*spcnt*/
                     + (size_t)BB * DMD * 2 /*smean+smax*/ + (size_t)BB * 4096 /*Dst*/
                     + NB * 32 /*a_g*/ + NB * 32 /*c_g*/ + NB /*gpart*/;
  const size_t FIXED_BYTES = fixedFloats * 4;          // ~35.1 MB
  const size_t SEG_UNIT = (size_t)BB * 4096 * 2;       // 512 KB per step (bf16)
  int S = 512;
  while (S > 1 && (size_t)S * SEG_UNIT + FIXED_BYTES > ws_size) S >>= 1;

  unsigned short* cand = (unsigned short*)d_ws;
  float* base = (float*)((char*)d_ws + (size_t)S * SEG_UNIT);
  float* chunk_h = base; base += CHEL;
  float* validf  = base; base += NB;
  float* lgu     = base; base += NB * 32;
  float* gu      = base; base += NB;
  float* spsum   = base; base += (size_t)BB * 64 * DMD;
  float* spmax   = base; base += (size_t)BB * 64 * DMD;
  float* spcnt   = base; base += (size_t)BB * 64;
  float* smean   = base; base += (size_t)BB * DMD;
  float* smaxv   = base; base += (size_t)BB * DMD;
  float* Dst     = base; base += (size_t)BB * 4096;
  float* a_g     = base; base += NB * 32;
  float* c_g     = base; base += NB * 32;
  float* gpart   = base; base += NB;
  float* out = (float*)d_out;
  fprintf(stderr, "[hsfc69] ws_size=%zu fixed=%zu S=%d total=%zu\n",
          ws_size, FIXED_BYTES, S, FIXED_BYTES + (size_t)S * SEG_UNIT);

  k_front<<<dim3(64, BB), dim3(256), 0, stream>>>(
      tokens, emb, in_w, in_b, c1w, c1b, c2w, c2b, op_w, op_b, on_w, on_b,
      un_w, un_b, wcu, wg, chunk_h, validf, lgu, gu, spsum, spmax, spcnt);
  k_surface<<<dim3(BB), dim3(128), 0, stream>>>(spsum, spmax, spcnt, smean, smaxv);
  k_accrec<<<dim3(16), dim3(256), 0, stream>>>(
      lgu, gu, validf, wcc, cn_w, cn_b, wg, bg, a_g, c_g, gpart);
  for (int j0 = 0; j0 < NCH; j0 += S) {
    k_cand<<<dim3(32, S), dim3(256), 0, stream>>>(chunk_h, c_g, wcdu, wcdc, bcdu, bcdc, cand, j0);
    k_scan_seg<<<dim3(BB), dim3(512), 0, stream>>>(
        chunk_h, a_g, c_g, gpart, validf, cand, j0, S,
        wg, base_D, Dst, smean, smaxv, cl_w, cl_b, f1w, f1b, f2w, f2b, out);
  }
}

// Round 5
// 3778.183 us; speedup vs baseline: 3.1173x; 1.0970x over previous
//
#include <hip/hip_runtime.h>
#include <hip/hip_bf16.h>
#include <cfloat>
#include <cstdio>

#define TT   2048
#define BB   64
#define DMD  128
#define CDD  32
#define NCH  512
#define FEATN 418
#define LDW  33     // padded leading dim for 128x32 LDS tiles in scan
#define APITCH 132  // front A-tile pitch (mult of 4 for aligned float4)
#define YPITCH 257  // front Y-tile pitch

// INJECTIVE bank-spreading swizzle for weight staging (8-float chunks):
// off(c) = c*8 + (c>>2)*4  — 4-float pad after every 4 chunks; 16B aligned;
// 16 lanes' ds_read_b128 land on 8 bank-quads at 2-way (free, m136).
#define WOFF(kk,c)  ((kk)*288 + (c)*8 + (((c)>>2)<<2))
#define WOFF2(kc,c) ((kc)*144 + (c)*8 + (((c)>>2)<<2))

// ---------------- helpers ----------------
__device__ __forceinline__ float redx16(float v) {
  v += __shfl_xor(v, 1); v += __shfl_xor(v, 2);
  v += __shfl_xor(v, 4); v += __shfl_xor(v, 8);
  return v;
}
__device__ __forceinline__ float redx32(float v) { v = redx16(v); v += __shfl_xor(v, 16); return v; }
__device__ __forceinline__ float redx64(float v) { v = redx32(v); v += __shfl_xor(v, 32); return v; }
__device__ __forceinline__ float bfbits2f(unsigned int u) {
  union { unsigned int i; float f; } v; v.i = u << 16; return v.f;
}
__device__ __forceinline__ unsigned short f2bf(float f) {
  union { float f; unsigned int i; } u; u.f = f;
  unsigned int r = u.i + 0x7FFFu + ((u.i >> 16) & 1u);
  return (unsigned short)(r >> 16);
}
__device__ __forceinline__ float sigmoidf_(float x) { return 1.f / (1.f + expf(-x)); }

__device__ __forceinline__ void load_cand8(const unsigned short* cand, size_t idx, float* pf) {
  uint4 v = *reinterpret_cast<const uint4*>(cand + idx);
  pf[0] = bfbits2f(v.x & 0xFFFFu); pf[1] = bfbits2f(v.x >> 16);
  pf[2] = bfbits2f(v.y & 0xFFFFu); pf[3] = bfbits2f(v.y >> 16);
  pf[4] = bfbits2f(v.z & 0xFFFFu); pf[5] = bfbits2f(v.z >> 16);
  pf[6] = bfbits2f(v.w & 0xFFFFu); pf[7] = bfbits2f(v.w >> 16);
}

typedef __attribute__((ext_vector_type(8))) short s8v;
typedef __attribute__((ext_vector_type(4))) float f4v;
union F8 { s8v v; unsigned short u[8]; uint4 q; };

// ============================================================================
// conv GEMM phase for k_front: swizzled Wl, dbuf, 1 barrier/kstep.
// ============================================================================
template<int KTOT, int ROWOFF, int YOFF>
__device__ __forceinline__ void conv_phase(
    const float* __restrict__ w, const float* __restrict__ bias,
    const float* A, float* Wl, float* Y, int t) {
  const int tm = t >> 4, tn = t & 15;
  const int r0 = tm * 2;
  const int kkw = t >> 5, cw = t & 31;
  float acc[2][16];
  #pragma unroll
  for (int m = 0; m < 2; ++m)
    #pragma unroll
    for (int q = 0; q < 16; ++q) acc[m][q] = 0.f;
  // prologue: stage kstep 0 into buf0
  {
    float4 wr0 = *reinterpret_cast<const float4*>(&w[(size_t)kkw * 256 + cw * 8]);
    float4 wr1 = *reinterpret_cast<const float4*>(&w[(size_t)kkw * 256 + cw * 8 + 4]);
    *reinterpret_cast<float4*>(&Wl[WOFF(kkw, cw)])     = wr0;
    *reinterpret_cast<float4*>(&Wl[WOFF(kkw, cw) + 4]) = wr1;
  }
  __syncthreads();
  for (int k0 = 0; k0 < KTOT; k0 += 8) {
    float* Wb = Wl + (((k0 >> 3) & 1) ? 2304 : 0);
    const bool more = (k0 + 8) < KTOT;
    float4 nr0, nr1;
    if (more) {
      nr0 = *reinterpret_cast<const float4*>(&w[(size_t)(k0 + 8 + kkw) * 256 + cw * 8]);
      nr1 = *reinterpret_cast<const float4*>(&w[(size_t)(k0 + 8 + kkw) * 256 + cw * 8 + 4]);
    }
    const int tap = k0 >> 7, ii0 = k0 & 127;   // tap constant within 8-block
    float a0v[8], a1v[8];
    const float* Ar0 = &A[(r0 + tap + ROWOFF) * APITCH + ii0];
    *reinterpret_cast<float4*>(&a0v[0]) = *reinterpret_cast<const float4*>(&Ar0[0]);
    *reinterpret_cast<float4*>(&a0v[4]) = *reinterpret_cast<const float4*>(&Ar0[4]);
    const float* Ar1 = Ar0 + APITCH;
    *reinterpret_cast<float4*>(&a1v[0]) = *reinterpret_cast<const float4*>(&Ar1[0]);
    *reinterpret_cast<float4*>(&a1v[4]) = *reinterpret_cast<const float4*>(&Ar1[4]);
    #pragma unroll
    for (int kk = 0; kk < 8; ++kk) {
      float w16[16];
      *reinterpret_cast<float4*>(&w16[0])  = *reinterpret_cast<float4*>(&Wb[WOFF(kk, tn)]);
      *reinterpret_cast<float4*>(&w16[4])  = *reinterpret_cast<float4*>(&Wb[WOFF(kk, tn) + 4]);
      *reinterpret_cast<float4*>(&w16[8])  = *reinterpret_cast<float4*>(&Wb[WOFF(kk, tn + 16)]);
      *reinterpret_cast<float4*>(&w16[12]) = *reinterpret_cast<float4*>(&Wb[WOFF(kk, tn + 16) + 4]);
      float a0 = a0v[kk], a1 = a1v[kk];
      #pragma unroll
      for (int q = 0; q < 16; ++q) { acc[0][q] += a0 * w16[q]; acc[1][q] += a1 * w16[q]; }
    }
    if (more) {
      float* Wn = Wl + ((((k0 >> 3) + 1) & 1) ? 2304 : 0);
      *reinterpret_cast<float4*>(&Wn[WOFF(kkw, cw)])     = nr0;
      *reinterpret_cast<float4*>(&Wn[WOFF(kkw, cw) + 4]) = nr1;
    }
    __syncthreads();
  }
  #pragma unroll
  for (int m = 0; m < 2; ++m)
    #pragma unroll
    for (int q = 0; q < 8; ++q) {
      float av = acc[m][q]     + bias[tn * 8 + q];
      float gv = acc[m][q + 8] + bias[128 + tn * 8 + q];
      Y[(r0 + m) * YPITCH + YOFF + tn * 8 + q] = av * sigmoidf_(gv);
    }
}

// ============================================================================
// k_front: per 32-position tile: embed+LN -> conv3/5+GLU -> op+residual+LN ->
// chunk means, validity, surface partials, ln(u)@wcu, u@wg.
// ============================================================================
__global__ __launch_bounds__(256) void k_front(
    const int* __restrict__ tokens, const float* __restrict__ emb,
    const float* __restrict__ inw, const float* __restrict__ inb,
    const float* __restrict__ c1w, const float* __restrict__ c1b,
    const float* __restrict__ c2w, const float* __restrict__ c2b,
    const float* __restrict__ opw, const float* __restrict__ opb,
    const float* __restrict__ onw, const float* __restrict__ onb,
    const float* __restrict__ unw, const float* __restrict__ unb,
    const float* __restrict__ wcu, const float* __restrict__ wgv,
    float* __restrict__ chunk_h, float* __restrict__ validf,
    float* __restrict__ lgu, float* __restrict__ gu,
    float* __restrict__ spsum, float* __restrict__ spmax, float* __restrict__ spcnt) {
  __shared__ float A[36 * APITCH];
  __shared__ float Y[32 * YPITCH];
  __shared__ float Wl[4608];       // dbuf: conv 2x2304, op 2x2304
  __shared__ float tokm[32];
  const int b = blockIdx.y, tile = blockIdx.x;
  const int t0 = tile * 32;
  const int t = threadIdx.x;
  const int lane = t & 63, wv = t >> 6;

  // ---- phase 0: embed + input LN into A ----
  for (int r = wv; r < 36; r += 4) {
    int p = t0 + r - 2;
    float2 o = make_float2(0.f, 0.f);
    if (p >= 0 && p < TT) {
      int tok = tokens[b * TT + p];
      if (lane == 0 && r >= 2 && r < 34) tokm[r - 2] = (tok != 0) ? 1.f : 0.f;
      float2 e = *reinterpret_cast<const float2*>(emb + (size_t)tok * DMD + lane * 2);
      float mean = redx64(e.x + e.y) * (1.f / 128.f);
      float d0 = e.x - mean, d1 = e.y - mean;
      float vvv = redx64(d0 * d0 + d1 * d1) * (1.f / 128.f);
      float rs = rsqrtf(vvv + 1e-5f);
      o.x = d0 * rs * inw[lane * 2]     + inb[lane * 2];
      o.y = d1 * rs * inw[lane * 2 + 1] + inb[lane * 2 + 1];
    }
    *reinterpret_cast<float2*>(&A[r * APITCH + lane * 2]) = o;
  }
  const int tm = t >> 4, tn = t & 15;
  const int r0 = tm * 2;

  // ---- phase 1: conv3 + GLU -> Y[:,0:128); conv5 + GLU -> Y[:,128:256) ----
  conv_phase<384, 1, 0>(c1w, c1b, A, Wl, Y, t);
  conv_phase<640, 0, 128>(c2w, c2b, A, Wl, Y, t);

  // ---- phase 2: op GEMM (Y @ op_w) + residual + LN -> h (registers) ----
  float acc2[2][8] = {};
  {
    const int kcw = t >> 4, cw2 = t & 15;
    {
      float4 wr0 = *reinterpret_cast<const float4*>(&opw[(size_t)kcw * 128 + cw2 * 8]);
      float4 wr1 = *reinterpret_cast<const float4*>(&opw[(size_t)kcw * 128 + cw2 * 8 + 4]);
      *reinterpret_cast<float4*>(&Wl[WOFF2(kcw, cw2)])     = wr0;
      *reinterpret_cast<float4*>(&Wl[WOFF2(kcw, cw2) + 4]) = wr1;
    }
    __syncthreads();  // also orders conv5's Y writes before op's Y reads
    for (int k0 = 0; k0 < 256; k0 += 16) {
      float* Wb = Wl + (((k0 >> 4) & 1) ? 2304 : 0);
      const bool more = (k0 + 16) < 256;
      float4 nr0, nr1;
      if (more) {
        nr0 = *reinterpret_cast<const float4*>(&opw[(size_t)(k0 + 16 + kcw) * 128 + cw2 * 8]);
        nr1 = *reinterpret_cast<const float4*>(&opw[(size_t)(k0 + 16 + kcw) * 128 + cw2 * 8 + 4]);
      }
      #pragma unroll
      for (int kc = 0; kc < 16; ++kc) {
        int k = k0 + kc;
        float y0 = Y[r0 * YPITCH + k];
        float y1 = Y[(r0 + 1) * YPITCH + k];
        float w8[8];
        *reinterpret_cast<float4*>(&w8[0]) = *reinterpret_cast<float4*>(&Wb[WOFF2(kc, tn)]);
        *reinterpret_cast<float4*>(&w8[4]) = *reinterpret_cast<float4*>(&Wb[WOFF2(kc, tn) + 4]);
        #pragma unroll
        for (int q = 0; q < 8; ++q) { acc2[0][q] += y0 * w8[q]; acc2[1][q] += y1 * w8[q]; }
      }
      if (more) {
        float* Wn = Wl + ((((k0 >> 4) + 1) & 1) ? 2304 : 0);
        *reinterpret_cast<float4*>(&Wn[WOFF2(kcw, cw2)])     = nr0;
        *reinterpret_cast<float4*>(&Wn[WOFF2(kcw, cw2) + 4]) = nr1;
      }
      __syncthreads();
    }
  }

  const int col = tn * 8;
  float hreg[2][8];
  float msk[2];
  #pragma unroll
  for (int m = 0; m < 2; ++m) {
    int row = r0 + m;
    float vals[8]; float s = 0.f;
    const float* xr = &A[(row + 2) * APITCH + col];
    #pragma unroll
    for (int q = 0; q < 8; ++q) { vals[q] = acc2[m][q] + opb[col + q] + xr[q]; s += vals[q]; }
    s = redx16(s);
    float mean = s * (1.f / 128.f);
    float vv2 = 0.f;
    #pragma unroll
    for (int q = 0; q < 8; ++q) { float d = vals[q] - mean; vv2 += d * d; }
    vv2 = redx16(vv2) * (1.f / 128.f);
    float rs = rsqrtf(vv2 + 1e-5f);
    #pragma unroll
    for (int q = 0; q < 8; ++q) hreg[m][q] = (vals[q] - mean) * rs * onw[col + q] + onb[col + q];
    msk[m] = tokm[row];
  }

  // ---- phase 3: surface partials + chunk means + lgu/gu ----
  float* partS = Y;               // 16*128
  float* partM = Y + 2048;        // 16*128
  float* lnus  = Y + 4096;        // 8*128
  float ps[8], pm[8];
  #pragma unroll
  for (int q = 0; q < 8; ++q) {
    ps[q] = msk[0] * hreg[0][q] + msk[1] * hreg[1][q];
    float m0 = (msk[0] != 0.f) ? hreg[0][q] : -FLT_MAX;
    float m1 = (msk[1] != 0.f) ? hreg[1][q] : -FLT_MAX;
    pm[q] = fmaxf(m0, m1);
  }
  #pragma unroll
  for (int q = 0; q < 8; ++q) { partS[tm * 128 + col + q] = ps[q]; partM[tm * 128 + col + q] = pm[q]; }

  float ccnt = msk[0] + msk[1];
  float csum[8];
  #pragma unroll
  for (int q = 0; q < 8; ++q) csum[q] = ps[q];
  #pragma unroll
  for (int q = 0; q < 8; ++q) csum[q] += __shfl_xor(csum[q], 16);
  ccnt += __shfl_xor(ccnt, 16);

  if ((tm & 1) == 0) {
    int jg = tile * 8 + (tm >> 1);
    float inv = 1.f / fmaxf(ccnt, 1.f);
    float cm[8];
    #pragma unroll
    for (int q = 0; q < 8; ++q) cm[q] = csum[q] * inv;
    *reinterpret_cast<float4*>(&chunk_h[((size_t)b * NCH + jg) * DMD + col])     = *reinterpret_cast<float4*>(&cm[0]);
    *reinterpret_cast<float4*>(&chunk_h[((size_t)b * NCH + jg) * DMD + col + 4]) = *reinterpret_cast<float4*>(&cm[4]);
    if (tn == 0) validf[jg * BB + b] = (ccnt > 0.f) ? 1.f : 0.f;
    float gp = 0.f;
    #pragma unroll
    for (int q = 0; q < 8; ++q) gp += cm[q] * wgv[col + q];
    gp = redx16(gp);
    if (tn == 0) gu[(size_t)jg * BB + b] = gp;
    float s2 = 0.f;
    #pragma unroll
    for (int q = 0; q < 8; ++q) s2 += cm[q];
    s2 = redx16(s2);
    float mean2 = s2 * (1.f / 128.f);
    float v3 = 0.f;
    #pragma unroll
    for (int q = 0; q < 8; ++q) { float d = cm[q] - mean2; v3 += d * d; }
    v3 = redx16(v3) * (1.f / 128.f);
    float rs2 = rsqrtf(v3 + 1e-5f);
    int ch = tm >> 1;
    #pragma unroll
    for (int q = 0; q < 8; ++q) lnus[ch * 128 + col + q] = (cm[q] - mean2) * rs2 * unw[col + q] + unb[col + q];
  }
  __syncthreads();
  {
    int ch = t >> 5, o = t & 31;
    float accl = 0.f;
    for (int d = 0; d < 128; ++d) accl += lnus[ch * 128 + d] * wcu[d * 32 + o];
    int jg2 = tile * 8 + ch;
    lgu[((size_t)jg2 * BB + b) * 32 + o] = accl;
  }
  if (t < 128) {
    float s3 = 0.f, m3 = -FLT_MAX;
    #pragma unroll
    for (int g = 0; g < 16; ++g) { s3 += partS[g * 128 + t]; m3 = fmaxf(m3, partM[g * 128 + t]); }
    spsum[((size_t)b * 64 + tile) * DMD + t] = s3;
    spmax[((size_t)b * 64 + tile) * DMD + t] = m3;
  }
  if (t == 128) {
    float cnt = 0.f;
    for (int r = 0; r < 32; ++r) cnt += tokm[r];
    spcnt[b * 64 + tile] = cnt;
  }
}

// ---------------- surface finalize ----------------
__global__ __launch_bounds__(128) void k_surface(
    const float* __restrict__ spsum, const float* __restrict__ spmax, const float* __restrict__ spcnt,
    float* __restrict__ smean, float* __restrict__ smax) {
  const int b = blockIdx.x, d = threadIdx.x;
  float s = 0.f, m = -FLT_MAX, cnt = 0.f;
  for (int p = 0; p < 64; ++p) {
    s += spsum[((size_t)b * 64 + p) * DMD + d];
    m = fmaxf(m, spmax[((size_t)b * 64 + p) * DMD + d]);
    cnt += spcnt[b * 64 + p];
  }
  smean[b * DMD + d] = s / fmaxf(cnt, 1.f);
  smax[b * DMD + d] = (cnt > 0.f) ? m : 0.f;
}

// ============================================================================
// k_prep_w: swizzle [wcdu;wcdc] (160x4096 fp32) into per-lane MFMA B-fragment
// order, split into bf16 hi/lo. One thread per (nt, ks, lane) -> 16B write.
// ============================================================================
__global__ __launch_bounds__(256) void k_prep_w(
    const float* __restrict__ wcdu, const float* __restrict__ wcdc,
    unsigned short* __restrict__ Whi, unsigned short* __restrict__ Wlo) {
  int tid = blockIdx.x * 256 + threadIdx.x;     // 81920 total
  int lane = tid & 63;
  int ks = (tid >> 6) % 5;
  int nt = tid / 320;
  int col = nt * 16 + (lane & 15);
  int kbase = ks * 32 + (lane >> 4) * 8;
  F8 hi, lo;
  #pragma unroll
  for (int j = 0; j < 8; ++j) {
    int k = kbase + j;
    float wv = (k < 128) ? wcdu[(size_t)k * 4096 + col] : wcdc[(size_t)(k - 128) * 4096 + col];
    unsigned short h = f2bf(wv);
    hi.u[j] = h;
    lo.u[j] = f2bf(wv - bfbits2f(h));
  }
  *reinterpret_cast<uint4*>(Whi + (size_t)tid * 8) = hi.q;
  *reinterpret_cast<uint4*>(Wlo + (size_t)tid * 8) = lo.q;
}

// ============================================================================
// k_cand_mfma: cand = [u|c_t] @ [wcdu;wcdc] + biases via bf16x3 MFMA.
// grid (16 ntiles, S); 4 waves; wave w owns 64 cols x all 64 rows. No LDS.
// ============================================================================
__global__ __launch_bounds__(256) void k_cand_mfma(
    const float* __restrict__ chunk_h, const float* __restrict__ c_g,
    const unsigned short* __restrict__ Whi, const unsigned short* __restrict__ Wlo,
    const float* __restrict__ bcdu, const float* __restrict__ bcdc,
    unsigned short* __restrict__ cand, int j0) {
  const int lj = blockIdx.y, j = j0 + lj;
  const int w = threadIdx.x >> 6, l = threadIdx.x & 63;
  const int nb = blockIdx.x * 256 + w * 64;
  const int l16 = l & 15, lk = l >> 4;
  f4v acc[4][4];
  #pragma unroll
  for (int mf = 0; mf < 4; ++mf)
    #pragma unroll
    for (int nf = 0; nf < 4; ++nf) acc[mf][nf] = (f4v)(0.f);
  #pragma unroll
  for (int ks = 0; ks < 5; ++ks) {
    F8 ahi[4], alo[4];
    #pragma unroll
    for (int mf = 0; mf < 4; ++mf) {
      int row = mf * 16 + l16;   // batch index
      float av[8];
      if (ks < 4) {
        const float* src = chunk_h + ((size_t)row * NCH + j) * DMD + ks * 32 + lk * 8;
        *reinterpret_cast<float4*>(&av[0]) = *reinterpret_cast<const float4*>(src);
        *reinterpret_cast<float4*>(&av[4]) = *reinterpret_cast<const float4*>(src + 4);
      } else {
        const float* src = c_g + ((size_t)j * BB + row) * 32 + lk * 8;
        *reinterpret_cast<float4*>(&av[0]) = *reinterpret_cast<const float4*>(src);
        *reinterpret_cast<float4*>(&av[4]) = *reinterpret_cast<const float4*>(src + 4);
      }
      #pragma unroll
      for (int q = 0; q < 8; ++q) {
        unsigned short h = f2bf(av[q]);
        ahi[mf].u[q] = h;
        alo[mf].u[q] = f2bf(av[q] - bfbits2f(h));
      }
    }
    #pragma unroll
    for (int nf = 0; nf < 4; ++nf) {
      int nt = (nb >> 4) + nf;
      size_t off = (((size_t)nt * 5 + ks) * 64 + l) * 8;
      F8 bhi, blo;
      bhi.q = *reinterpret_cast<const uint4*>(Whi + off);
      blo.q = *reinterpret_cast<const uint4*>(Wlo + off);
      #pragma unroll
      for (int mf = 0; mf < 4; ++mf) {
        acc[mf][nf] = __builtin_amdgcn_mfma_f32_16x16x32_bf16(ahi[mf].v, bhi.v, acc[mf][nf], 0, 0, 0);
        acc[mf][nf] = __builtin_amdgcn_mfma_f32_16x16x32_bf16(ahi[mf].v, blo.v, acc[mf][nf], 0, 0, 0);
        acc[mf][nf] = __builtin_amdgcn_mfma_f32_16x16x32_bf16(alo[mf].v, bhi.v, acc[mf][nf], 0, 0, 0);
      }
    }
  }
  #pragma unroll
  for (int nf = 0; nf < 4; ++nf) {
    int colc = nb + nf * 16 + l16;
    float bias = bcdu[colc] + bcdc[colc];
    #pragma unroll
    for (int mf = 0; mf < 4; ++mf) {
      #pragma unroll
      for (int r = 0; r < 4; ++r) {
        int row = mf * 16 + lk * 4 + r;
        cand[((size_t)lj * BB + row) * 4096 + colc] = f2bf(acc[mf][nf][r] + bias);
      }
    }
  }
}

// ============================================================================
// k_accrec: the closed (a, c) recurrence. One wave per batch; prefetched
// next-step inputs (recurrence-independent); no barriers in the loop.
// ============================================================================
__global__ __launch_bounds__(64) void k_accrec(
    const float* __restrict__ lgu, const float* __restrict__ gu,
    const float* __restrict__ validf,
    const float* __restrict__ wcc, const float* __restrict__ cnw, const float* __restrict__ cnb,
    const float* __restrict__ wg, const float* __restrict__ bg,
    float* __restrict__ a_g, float* __restrict__ c_g, float* __restrict__ gpart_g) {
  __shared__ float wcc_l[CDD * CDD];
  __shared__ float cn_s[CDD];
  __shared__ float as_s[CDD];
  const int t = threadIdx.x, l = t & 31;
  const int b = blockIdx.x;
  for (int i = t; i < CDD * CDD; i += 64) wcc_l[i] = wcc[i];
  __syncthreads();
  const float cw = cnw[l], cb = cnb[l], wgc = wg[DMD + l];
  const float bgs = bg[0];
  float c = 0.f;
  float lg = lgu[(size_t)b * 32 + l];
  float vld = validf[b];
  float guv = gu[b];
  for (int j = 0; j < NCH; ++j) {
    const int jn = (j + 1 < NCH) ? j + 1 : j;
    const size_t jbn = (size_t)jn * BB + b;
    float lgN = lgu[jbn * 32 + l];
    float vldN = validf[jbn];
    float guvN = gu[jbn];
    // ln(c)
    float mean = redx32(c) * (1.f / 32.f);
    float dv = c - mean;
    float var = redx32(dv * dv) * (1.f / 32.f);
    float cn = dv * rsqrtf(var + 1e-5f) * cw + cb;
    if (t < 32) cn_s[l] = cn;
    float l0 = lg, l1 = 0.f;
    #pragma unroll
    for (int i = 0; i < 16; ++i) {
      l0 += cn_s[i] * wcc_l[i * 32 + l];
      l1 += cn_s[i + 16] * wcc_l[(i + 16) * 32 + l];
    }
    float logit = l0 + l1;
    float sv = (logit > 0.05f) ? (logit - 0.05f) : ((logit < -0.05f) ? (logit + 0.05f) : 0.f);
    float as = fabsf(sv);
    if (t < 32) as_s[l] = as;
    int r0 = 0, r1 = 0;
    #pragma unroll
    for (int i = 0; i < 16; ++i) {
      float a0 = as_s[i], a1 = as_s[i + 16];
      r0 += (a0 > as || (a0 == as && i < l)) ? 1 : 0;
      r1 += (a1 > as || (a1 == as && (i + 16) < l)) ? 1 : 0;
    }
    float av = ((r0 + r1) < 8) ? sv : 0.f;
    float ct = (vld != 0.f) ? (0.9f * c + 0.1f * av) : c;
    c = ct;
    float dotc = redx32(ct * wgc);
    if (t < 32) {
      const size_t jb = (size_t)j * BB + b;
      a_g[jb * 32 + l] = av;
      c_g[jb * 32 + l] = ct;
      if (l == 0) gpart_g[jb] = guv + dotc + bgs;
    }
    lg = lgN; vld = vldN; guv = guvN;
  }
}

// ============================================================================
// k_scan_seg: D-only recurrence, 2 barriers/step, D in registers.
// ============================================================================
__global__ __launch_bounds__(512) void k_scan_seg(
    const float* __restrict__ chunk_h, const float* __restrict__ a_gg,
    const float* __restrict__ c_g, const float* __restrict__ gpart_g,
    const float* __restrict__ validf,
    const unsigned short* __restrict__ cand, int j0, int slen,
    const float* __restrict__ wg, const float* __restrict__ base_D,
    float* __restrict__ Dst,
    const float* __restrict__ smean, const float* __restrict__ smax,
    const float* __restrict__ clw, const float* __restrict__ clb,
    const float* __restrict__ f1w, const float* __restrict__ f1b,
    const float* __restrict__ f2w, const float* __restrict__ f2b,
    float* __restrict__ out) {
  __shared__ float Dl[DMD * LDW];
  __shared__ float Cl[DMD * LDW];
  __shared__ float a_l[CDD];
  __shared__ float r_l[DMD];
  __shared__ float red[8];
  __shared__ float feat[FEATN + 2];
  __shared__ float featn[FEATN + 2];
  __shared__ float h1[256];

  const int b = blockIdx.x;
  const int t = threadIdx.x;
  const int c = t >> 4;
  const int rg = t & 15;
  const bool doInit = (j0 == 0);
  const bool doHead = (j0 + slen >= NCH);
  const float wge = wg[160];

  if (doInit) {
    for (int i = t; i < DMD * CDD; i += 512) Dl[(i >> 5) * LDW + (i & 31)] = base_D[i];
  } else {
    for (int i = t; i < DMD * CDD; i += 512) Dl[(i >> 5) * LDW + (i & 31)] = Dst[(size_t)b * 4096 + i];
  }
  __syncthreads();
  float Dv[8];
  if (doInit) {
    float s = 0.f;
    #pragma unroll
    for (int m = 0; m < 8; ++m) { Dv[m] = Dl[(rg + 16 * m) * LDW + c]; s += Dv[m] * Dv[m]; }
    s = redx16(s);
    float inv = 1.f / fmaxf(sqrtf(s), 1e-12f);
    #pragma unroll
    for (int m = 0; m < 8; ++m) { Dv[m] *= inv; Dl[(rg + 16 * m) * LDW + c] = Dv[m]; }
  } else {
    #pragma unroll
    for (int m = 0; m < 8; ++m) Dv[m] = Dl[(rg + 16 * m) * LDW + c];
  }
  float pf[8];
  load_cand8(cand, ((size_t)0 * BB + b) * 4096 + (size_t)t * 8, pf);
  float un_r = (t < DMD) ? chunk_h[((size_t)b * NCH + j0) * DMD + t] : 0.f;
  float a_col = a_gg[((size_t)j0 * BB + b) * 32 + c];
  if (t < 32) a_l[t] = a_gg[((size_t)j0 * BB + b) * 32 + t];
  float gpart = gpart_g[(size_t)j0 * BB + b];
  float vld = validf[(size_t)j0 * BB + b];
  float err = 0.f, gate = 0.f;

  for (int lj = 0; lj < slen; ++lj) {
    __syncthreads(); // B1
    {
      int dd = t >> 2, cc0 = (t & 3) * 8;
      #pragma unroll
      for (int q = 0; q < 8; ++q) Cl[dd * LDW + cc0 + q] = pf[q];
    }
    if (t < DMD) {
      float uh = 0.f;
      #pragma unroll
      for (int cc = 0; cc < 32; ++cc) uh += a_l[cc] * Dl[t * LDW + cc];
      float rr = un_r - uh;
      r_l[t] = rr;
      float rp = redx64(rr * rr);
      if ((t & 63) == 0) red[t >> 6] = rp;
    }
    __syncthreads(); // B2
    err = sqrtf(red[0] + red[1]);
    gate = sigmoidf_(gpart + err * wge);
    const int ljn = (lj + 1 < slen) ? (lj + 1) : lj;
    const int jn = j0 + ljn;
    float pfN[8];
    load_cand8(cand, ((size_t)ljn * BB + b) * 4096 + (size_t)t * 8, pfN);
    float unN = (t < DMD) ? chunk_h[((size_t)b * NCH + jn) * DMD + t] : 0.f;
    float aColN = a_gg[((size_t)jn * BB + b) * 32 + c];
    float a32N = (t < 32) ? a_gg[((size_t)jn * BB + b) * 32 + t] : 0.f;
    float gpN = gpart_g[(size_t)jn * BB + b];
    float vldN = validf[(size_t)jn * BB + b];
    float dl[8], dcv[8], dn[8];
    float sl = 0.f, sc = 0.f;
    #pragma unroll
    for (int m = 0; m < 8; ++m) {
      int e = (rg + 16 * m) * LDW + c;
      dl[m] = Dv[m] + 0.03f * r_l[rg + 16 * m] * a_col;
      sl += dl[m] * dl[m];
      dcv[m] = Cl[e];
      sc += dcv[m] * dcv[m];
    }
    sl = redx16(sl); sc = redx16(sc);
    float il = 1.f / fmaxf(sqrtf(sl), 1e-12f);
    float ic = 1.f / fmaxf(sqrtf(sc), 1e-12f);
    float g1 = 1.f - gate;
    float sn = 0.f;
    #pragma unroll
    for (int m = 0; m < 8; ++m) { dn[m] = g1 * dl[m] * il + gate * dcv[m] * ic; sn += dn[m] * dn[m]; }
    sn = redx16(sn);
    float inn = 1.f / fmaxf(sqrtf(sn), 1e-12f);
    const bool vb = (vld != 0.f);
    #pragma unroll
    for (int m = 0; m < 8; ++m) {
      if (vb) Dv[m] = dn[m] * inn;
      Dl[(rg + 16 * m) * LDW + c] = Dv[m];
    }
    if (t < 32) a_l[t] = a32N;
    #pragma unroll
    for (int q = 0; q < 8; ++q) pf[q] = pfN[q];
    un_r = unN; a_col = aColN; gpart = gpN; vld = vldN;
  }
  __syncthreads();
  for (int i = t; i < 4096; i += 512) Dst[(size_t)b * 4096 + i] = Dl[(i >> 5) * LDW + (i & 31)];
  if (!doHead) return;
  if (t < 32) a_l[t] = c_g[((size_t)(NCH - 1) * BB + b) * 32 + t];
  __syncthreads();
  if (t < DMD) {
    float z = 0.f;
    #pragma unroll
    for (int cc = 0; cc < 32; ++cc) z += Dl[t * LDW + cc] * a_l[cc];
    feat[t] = z;
    feat[160 + t] = smean[b * DMD + t];
    feat[288 + t] = smax[b * DMD + t];
  }
  if (t >= 128 && t < 160) feat[t] = a_l[t - 128];
  if (t == 0) { feat[416] = err; feat[417] = gate; }
  __syncthreads();
  float fv = (t < FEATN) ? feat[t] : 0.f;
  float ws1 = redx64(fv);
  if ((t & 63) == 0) red[t >> 6] = ws1;
  __syncthreads();
  float tot = 0.f;
  #pragma unroll
  for (int w = 0; w < 8; ++w) tot += red[w];
  float mean = tot * (1.f / 418.f);
  float dvv = (t < FEATN) ? (fv - mean) : 0.f;
  float ws2 = redx64(dvv * dvv);
  __syncthreads();
  if ((t & 63) == 0) red[t >> 6] = ws2;
  __syncthreads();
  float vtot = 0.f;
  #pragma unroll
  for (int w = 0; w < 8; ++w) vtot += red[w];
  float rs = rsqrtf(vtot * (1.f / 418.f) + 1e-5f);
  if (t < FEATN) featn[t] = (fv - mean) * rs * clw[t] + clb[t];
  __syncthreads();
  if (t < 256) {
    float acc = f1b[t];
    for (int f = 0; f < FEATN; ++f) acc += featn[f] * f1w[(size_t)f * 256 + t];
    h1[t] = acc * 0.5f * (1.f + erff(acc * 0.70710678f));
  }
  __syncthreads();
  if (t < 8) {
    float acc = f2b[t];
    #pragma unroll 8
    for (int i = 0; i < 256; ++i) acc += h1[i] * f2w[i * 8 + t];
    out[b * 8 + t] = acc;
  }
}

// ---------------- launch ----------------
extern "C" void kernel_launch(void* const* d_in, const int* in_sizes, int n_in,
                              void* d_out, int out_size, void* d_ws, size_t ws_size,
                              hipStream_t stream) {
  const int*   tokens = (const int*)d_in[0];
  const float* emb    = (const float*)d_in[1];
  const float* in_w   = (const float*)d_in[2];
  const float* in_b   = (const float*)d_in[3];
  const float* c1w    = (const float*)d_in[4];
  const float* c1b    = (const float*)d_in[5];
  const float* c2w    = (const float*)d_in[6];
  const float* c2b    = (const float*)d_in[7];
  const float* op_w   = (const float*)d_in[8];
  const float* op_b   = (const float*)d_in[9];
  const float* on_w   = (const float*)d_in[10];
  const float* on_b   = (const float*)d_in[11];
  const float* base_D = (const float*)d_in[12];
  const float* wcu    = (const float*)d_in[13];
  const float* wcc    = (const float*)d_in[14];
  const float* wcdu   = (const float*)d_in[15];
  const float* bcdu   = (const float*)d_in[16];
  const float* wcdc   = (const float*)d_in[17];
  const float* bcdc   = (const float*)d_in[18];
  const float* wg     = (const float*)d_in[19];
  const float* bg     = (const float*)d_in[20];
  const float* un_w   = (const float*)d_in[21];
  const float* un_b   = (const float*)d_in[22];
  const float* cn_w   = (const float*)d_in[23];
  const float* cn_b   = (const float*)d_in[24];
  const float* cl_w   = (const float*)d_in[25];
  const float* cl_b   = (const float*)d_in[26];
  const float* f1w    = (const float*)d_in[27];
  const float* f1b    = (const float*)d_in[28];
  const float* f2w    = (const float*)d_in[29];
  const float* f2b    = (const float*)d_in[30];

  // ---- adaptive workspace layout ----
  const size_t CHEL = (size_t)BB * NCH * DMD;
  const size_t NB   = (size_t)NCH * BB;
  size_t fixedFloats = CHEL + NB + NB * 32 + NB
                     + (size_t)BB * 64 * DMD * 2 + (size_t)BB * 64
                     + (size_t)BB * DMD * 2 + (size_t)BB * 4096
                     + NB * 32 + NB * 32 + NB;
  const size_t WFRAG = 655360ull;                       // ushorts per copy
  const size_t WSWZ_BYTES = 2ull * WFRAG * 2ull;        // hi + lo
  const size_t FIXED_BYTES = fixedFloats * 4 + WSWZ_BYTES;
  const size_t SEG_UNIT = (size_t)BB * 4096 * 2;        // 512 KB per step
  int S = 512;
  while (S > 1 && (size_t)S * SEG_UNIT + FIXED_BYTES > ws_size) S >>= 1;

  unsigned short* cand = (unsigned short*)d_ws;
  unsigned short* Whi = (unsigned short*)((char*)d_ws + (size_t)S * SEG_UNIT);
  unsigned short* Wlo = Whi + WFRAG;
  float* base = (float*)((char*)Wlo + WFRAG * 2);
  float* chunk_h = base; base += CHEL;
  float* validf  = base; base += NB;
  float* lgu     = base; base += NB * 32;
  float* gu      = base; base += NB;
  float* spsum   = base; base += (size_t)BB * 64 * DMD;
  float* spmax   = base; base += (size_t)BB * 64 * DMD;
  float* spcnt   = base; base += (size_t)BB * 64;
  float* smean   = base; base += (size_t)BB * DMD;
  float* smaxv   = base; base += (size_t)BB * DMD;
  float* Dst     = base; base += (size_t)BB * 4096;
  float* a_g     = base; base += NB * 32;
  float* c_g     = base; base += NB * 32;
  float* gpart   = base; base += NB;
  float* out = (float*)d_out;
  fprintf(stderr, "[hsfc69] ws_size=%zu fixed=%zu S=%d total=%zu\n",
          ws_size, FIXED_BYTES, S, FIXED_BYTES + (size_t)S * SEG_UNIT);

  k_prep_w<<<dim3(320), dim3(256), 0, stream>>>(wcdu, wcdc, Whi, Wlo);
  k_front<<<dim3(64, BB), dim3(256), 0, stream>>>(
      tokens, emb, in_w, in_b, c1w, c1b, c2w, c2b, op_w, op_b, on_w, on_b,
      un_w, un_b, wcu, wg, chunk_h, validf, lgu, gu, spsum, spmax, spcnt);
  k_surface<<<dim3(BB), dim3(128), 0, stream>>>(spsum, spmax, spcnt, smean, smaxv);
  k_accrec<<<dim3(BB), dim3(64), 0, stream>>>(
      lgu, gu, validf, wcc, cn_w, cn_b, wg, bg, a_g, c_g, gpart);
  for (int j0 = 0; j0 < NCH; j0 += S) {
    k_cand_mfma<<<dim3(16, S), dim3(256), 0, stream>>>(
        chunk_h, c_g, Whi, Wlo, bcdu, bcdc, cand, j0);
    k_scan_seg<<<dim3(BB), dim3(512), 0, stream>>>(
        chunk_h, a_g, c_g, gpart, validf, cand, j0, S,
        wg, base_D, Dst, smean, smaxv, cl_w, cl_b, f1w, f1b, f2w, f2b, out);
  }
}

// Round 6
// 2995.118 us; speedup vs baseline: 3.9323x; 1.2614x over previous
//
#include <hip/hip_runtime.h>
#include <hip/hip_bf16.h>
#include <cfloat>
#include <cstdio>

#define TT   2048
#define BB   64
#define DMD  128
#define CDD  32
#define NCH  512
#define FEATN 418
#define LDW  33     // padded leading dim for 128x32 LDS tiles in scan
#define APITCH 132  // front A-tile pitch (mult of 4 for aligned float4)
#define YPITCH 257  // front Y-tile pitch

// injective bank-spreading swizzle for op weight staging (8-float chunks)
#define WOFF2(kc,c) ((kc)*144 + (c)*8 + (((c)>>2)<<2))

// ---------------- helpers ----------------
__device__ __forceinline__ float redx16(float v) {
  v += __shfl_xor(v, 1); v += __shfl_xor(v, 2);
  v += __shfl_xor(v, 4); v += __shfl_xor(v, 8);
  return v;
}
__device__ __forceinline__ float redx32(float v) { v = redx16(v); v += __shfl_xor(v, 16); return v; }
__device__ __forceinline__ float redx64(float v) { v = redx32(v); v += __shfl_xor(v, 32); return v; }
__device__ __forceinline__ float bfbits2f(unsigned int u) {
  union { unsigned int i; float f; } v; v.i = u << 16; return v.f;
}
__device__ __forceinline__ unsigned short f2bf(float f) {
  union { float f; unsigned int i; } u; u.f = f;
  unsigned int r = u.i + 0x7FFFu + ((u.i >> 16) & 1u);
  return (unsigned short)(r >> 16);
}
__device__ __forceinline__ float sigmoidf_(float x) { return 1.f / (1.f + expf(-x)); }

__device__ __forceinline__ void load_cand8(const unsigned short* cand, size_t idx, float* pf) {
  uint4 v = *reinterpret_cast<const uint4*>(cand + idx);
  pf[0] = bfbits2f(v.x & 0xFFFFu); pf[1] = bfbits2f(v.x >> 16);
  pf[2] = bfbits2f(v.y & 0xFFFFu); pf[3] = bfbits2f(v.y >> 16);
  pf[4] = bfbits2f(v.z & 0xFFFFu); pf[5] = bfbits2f(v.z >> 16);
  pf[6] = bfbits2f(v.w & 0xFFFFu); pf[7] = bfbits2f(v.w >> 16);
}

typedef __attribute__((ext_vector_type(8))) short s8v;
typedef __attribute__((ext_vector_type(4))) float f4v;
union F8 { s8v v; unsigned short u[8]; uint4 q; };

// ============================================================================
// k_prep_conv: swizzle conv weights into MFMA B-fragment lane order, bf16
// hi/lo. frag id = ((tap*4+kc)*16+nt)*64+lane; value = W[tap*128+kc*32+
// (lane>>4)*8+j][nt*16+(lane&15)]. Same verified mapping as k_prep_w.
// ============================================================================
__global__ __launch_bounds__(256) void k_prep_conv(
    const float* __restrict__ c1w, const float* __restrict__ c2w,
    unsigned short* __restrict__ W3hi, unsigned short* __restrict__ W3lo,
    unsigned short* __restrict__ W5hi, unsigned short* __restrict__ W5lo) {
  int tid = blockIdx.x * 256 + threadIdx.x;   // 32768 total
  const float* src; unsigned short *dh, *dl; int fid;
  if (tid < 12288) { fid = tid;        src = c1w; dh = W3hi; dl = W3lo; }
  else             { fid = tid - 12288; src = c2w; dh = W5hi; dl = W5lo; }
  int lane = fid & 63;
  int nt   = (fid >> 6) & 15;
  int kc   = (fid >> 10) & 3;
  int tap  = fid >> 12;
  int col  = nt * 16 + (lane & 15);
  int kb   = tap * 128 + kc * 32 + (lane >> 4) * 8;
  F8 hi, lo;
  #pragma unroll
  for (int j = 0; j < 8; ++j) {
    float wv = src[(size_t)(kb + j) * 256 + col];
    unsigned short h = f2bf(wv);
    hi.u[j] = h;
    lo.u[j] = f2bf(wv - bfbits2f(h));
  }
  *reinterpret_cast<uint4*>(dh + (size_t)fid * 8) = hi.q;
  *reinterpret_cast<uint4*>(dl + (size_t)fid * 8) = lo.q;
}

// ============================================================================
// k_front: per 32-position tile: embed+LN -> conv3/5 via bf16x4 MFMA + GLU ->
// op GEMM (fp32) + residual + LN -> chunk means, surface partials, lgu/gu.
// ============================================================================
__global__ __launch_bounds__(256) void k_front(
    const int* __restrict__ tokens, const float* __restrict__ emb,
    const float* __restrict__ inw, const float* __restrict__ inb,
    const unsigned short* __restrict__ W3hi, const unsigned short* __restrict__ W3lo,
    const unsigned short* __restrict__ W5hi, const unsigned short* __restrict__ W5lo,
    const float* __restrict__ c1b, const float* __restrict__ c2b,
    const float* __restrict__ opw, const float* __restrict__ opb,
    const float* __restrict__ onw, const float* __restrict__ onb,
    const float* __restrict__ unw, const float* __restrict__ unb,
    const float* __restrict__ wcu, const float* __restrict__ wgv,
    float* __restrict__ chunk_h, float* __restrict__ validf,
    float* __restrict__ lgu, float* __restrict__ gu,
    float* __restrict__ spsum, float* __restrict__ spmax, float* __restrict__ spcnt) {
  __shared__ float A[36 * APITCH];     // fp32 x tile (residual + reference)
  __shared__ float Y[32 * YPITCH];     // GLU outputs fp32; later partials/lnus
  __shared__ float ABf[4608];          // phase1: Ahi/Alo bf16; phase2: op Wl dbuf
  __shared__ float tokm[32];
  unsigned short* Ahi = (unsigned short*)ABf;        // 36*128 shorts, swizzled
  unsigned short* Alo = Ahi + 36 * 128;
  const int b = blockIdx.y, tile = blockIdx.x;
  const int t0 = tile * 32;
  const int t = threadIdx.x;
  const int lane = t & 63, wq = t >> 6;

  // ---- phase 0: embed + input LN into A (fp32) and Ahi/Alo (bf16, swizzled) ----
  for (int r = wq; r < 36; r += 4) {
    int p = t0 + r - 2;
    float2 o = make_float2(0.f, 0.f);
    if (p >= 0 && p < TT) {
      int tok = tokens[b * TT + p];
      if (lane == 0 && r >= 2 && r < 34) tokm[r - 2] = (tok != 0) ? 1.f : 0.f;
      float2 e = *reinterpret_cast<const float2*>(emb + (size_t)tok * DMD + lane * 2);
      float mean = redx64(e.x + e.y) * (1.f / 128.f);
      float d0 = e.x - mean, d1 = e.y - mean;
      float vvv = redx64(d0 * d0 + d1 * d1) * (1.f / 128.f);
      float rs = rsqrtf(vvv + 1e-5f);
      o.x = d0 * rs * inw[lane * 2]     + inb[lane * 2];
      o.y = d1 * rs * inw[lane * 2 + 1] + inb[lane * 2 + 1];
    }
    *reinterpret_cast<float2*>(&A[r * APITCH + lane * 2]) = o;
    // bf16 hi/lo, swizzled: slot = (ch>>3) ^ (r&7)
    unsigned short hx = f2bf(o.x), hy = f2bf(o.y);
    unsigned short lx = f2bf(o.x - bfbits2f(hx)), ly = f2bf(o.y - bfbits2f(hy));
    int slot = (lane >> 2) ^ (r & 7);
    int ui = r * 64 + slot * 4 + (lane & 3);
    ((unsigned int*)Ahi)[ui] = (unsigned int)hx | ((unsigned int)hy << 16);
    ((unsigned int*)Alo)[ui] = (unsigned int)lx | ((unsigned int)ly << 16);
  }
  __syncthreads();

  // ---- phase 1: conv3 + conv5 via bf16x4 MFMA, shared A-fragments ----
  // wave wq owns av cols [wq*32, wq*32+32) and gv cols [128+wq*32, ...)
  const int l16 = lane & 15, lk = lane >> 4;
  f4v acc3[2][4], acc5[2][4];
  #pragma unroll
  for (int mt = 0; mt < 2; ++mt)
    #pragma unroll
    for (int nf = 0; nf < 4; ++nf) { acc3[mt][nf] = (f4v)(0.f); acc5[mt][nf] = (f4v)(0.f); }
  #pragma unroll
  for (int d = 0; d < 5; ++d) {           // A row offset; conv5 tap=d, conv3 tap=d-1
    #pragma unroll
    for (int kc = 0; kc < 4; ++kc) {
      F8 ahi[2], alo[2];
      #pragma unroll
      for (int mt = 0; mt < 2; ++mt) {
        int arow = mt * 16 + l16 + d;
        int s = (kc * 4 + lk) ^ (arow & 7);
        ahi[mt].q = *reinterpret_cast<const uint4*>(Ahi + arow * 128 + s * 8);
        alo[mt].q = *reinterpret_cast<const uint4*>(Alo + arow * 128 + s * 8);
      }
      #pragma unroll
      for (int nf = 0; nf < 4; ++nf) {
        int nt = (nf < 2) ? (wq * 2 + nf) : (8 + wq * 2 + nf - 2);
        size_t off = ((size_t)((d * 4 + kc) * 16 + nt) * 64 + lane) * 8;
        F8 bh, bl;
        bh.q = *reinterpret_cast<const uint4*>(W5hi + off);
        bl.q = *reinterpret_cast<const uint4*>(W5lo + off);
        #pragma unroll
        for (int mt = 0; mt < 2; ++mt) {
          acc5[mt][nf] = __builtin_amdgcn_mfma_f32_16x16x32_bf16(ahi[mt].v, bh.v, acc5[mt][nf], 0, 0, 0);
          acc5[mt][nf] = __builtin_amdgcn_mfma_f32_16x16x32_bf16(ahi[mt].v, bl.v, acc5[mt][nf], 0, 0, 0);
          acc5[mt][nf] = __builtin_amdgcn_mfma_f32_16x16x32_bf16(alo[mt].v, bh.v, acc5[mt][nf], 0, 0, 0);
          acc5[mt][nf] = __builtin_amdgcn_mfma_f32_16x16x32_bf16(alo[mt].v, bl.v, acc5[mt][nf], 0, 0, 0);
        }
      }
      if (d >= 1 && d <= 3) {
        int tap = d - 1;
        #pragma unroll
        for (int nf = 0; nf < 4; ++nf) {
          int nt = (nf < 2) ? (wq * 2 + nf) : (8 + wq * 2 + nf - 2);
          size_t off = ((size_t)((tap * 4 + kc) * 16 + nt) * 64 + lane) * 8;
          F8 bh, bl;
          bh.q = *reinterpret_cast<const uint4*>(W3hi + off);
          bl.q = *reinterpret_cast<const uint4*>(W3lo + off);
          #pragma unroll
          for (int mt = 0; mt < 2; ++mt) {
            acc3[mt][nf] = __builtin_amdgcn_mfma_f32_16x16x32_bf16(ahi[mt].v, bh.v, acc3[mt][nf], 0, 0, 0);
            acc3[mt][nf] = __builtin_amdgcn_mfma_f32_16x16x32_bf16(ahi[mt].v, bl.v, acc3[mt][nf], 0, 0, 0);
            acc3[mt][nf] = __builtin_amdgcn_mfma_f32_16x16x32_bf16(alo[mt].v, bh.v, acc3[mt][nf], 0, 0, 0);
            acc3[mt][nf] = __builtin_amdgcn_mfma_f32_16x16x32_bf16(alo[mt].v, bl.v, acc3[mt][nf], 0, 0, 0);
          }
        }
      }
    }
  }
  // GLU epilogue: C frag row = mt*16 + lk*4 + r, col = wq*32 + nf*16 + l16
  #pragma unroll
  for (int mt = 0; mt < 2; ++mt)
    #pragma unroll
    for (int nf = 0; nf < 2; ++nf) {
      int col = wq * 32 + nf * 16 + l16;
      #pragma unroll
      for (int r = 0; r < 4; ++r) {
        int row = mt * 16 + lk * 4 + r;
        float av3 = acc3[mt][nf][r]     + c1b[col];
        float gv3 = acc3[mt][nf + 2][r] + c1b[128 + col];
        Y[row * YPITCH + col] = av3 * sigmoidf_(gv3);
        float av5 = acc5[mt][nf][r]     + c2b[col];
        float gv5 = acc5[mt][nf + 2][r] + c2b[128 + col];
        Y[row * YPITCH + 128 + col] = av5 * sigmoidf_(gv5);
      }
    }
  __syncthreads();   // all ABf (Ahi/Alo) reads done; Y writes visible

  // ---- phase 2: op GEMM (fp32) + residual + LN -> h (registers) ----
  const int tm = t >> 4, tn = t & 15;
  const int r0 = tm * 2;
  float* Wl = ABf;   // reuse bf16 region as op weight dbuf (2 x 2304)
  float acc2[2][8] = {};
  {
    const int kcw = t >> 4, cw2 = t & 15;
    {
      float4 wr0 = *reinterpret_cast<const float4*>(&opw[(size_t)kcw * 128 + cw2 * 8]);
      float4 wr1 = *reinterpret_cast<const float4*>(&opw[(size_t)kcw * 128 + cw2 * 8 + 4]);
      *reinterpret_cast<float4*>(&Wl[WOFF2(kcw, cw2)])     = wr0;
      *reinterpret_cast<float4*>(&Wl[WOFF2(kcw, cw2) + 4]) = wr1;
    }
    __syncthreads();
    for (int k0 = 0; k0 < 256; k0 += 16) {
      float* Wb = Wl + (((k0 >> 4) & 1) ? 2304 : 0);
      const bool more = (k0 + 16) < 256;
      float4 nr0, nr1;
      if (more) {
        nr0 = *reinterpret_cast<const float4*>(&opw[(size_t)(k0 + 16 + kcw) * 128 + cw2 * 8]);
        nr1 = *reinterpret_cast<const float4*>(&opw[(size_t)(k0 + 16 + kcw) * 128 + cw2 * 8 + 4]);
      }
      #pragma unroll
      for (int kc = 0; kc < 16; ++kc) {
        int k = k0 + kc;
        float y0 = Y[r0 * YPITCH + k];
        float y1 = Y[(r0 + 1) * YPITCH + k];
        float w8[8];
        *reinterpret_cast<float4*>(&w8[0]) = *reinterpret_cast<float4*>(&Wb[WOFF2(kc, tn)]);
        *reinterpret_cast<float4*>(&w8[4]) = *reinterpret_cast<float4*>(&Wb[WOFF2(kc, tn) + 4]);
        #pragma unroll
        for (int q = 0; q < 8; ++q) { acc2[0][q] += y0 * w8[q]; acc2[1][q] += y1 * w8[q]; }
      }
      if (more) {
        float* Wn = Wl + ((((k0 >> 4) + 1) & 1) ? 2304 : 0);
        *reinterpret_cast<float4*>(&Wn[WOFF2(kcw, cw2)])     = nr0;
        *reinterpret_cast<float4*>(&Wn[WOFF2(kcw, cw2) + 4]) = nr1;
      }
      __syncthreads();
    }
  }

  const int col = tn * 8;
  float hreg[2][8];
  float msk[2];
  #pragma unroll
  for (int m = 0; m < 2; ++m) {
    int row = r0 + m;
    float vals[8]; float s = 0.f;
    const float* xr = &A[(row + 2) * APITCH + col];
    #pragma unroll
    for (int q = 0; q < 8; ++q) { vals[q] = acc2[m][q] + opb[col + q] + xr[q]; s += vals[q]; }
    s = redx16(s);
    float mean = s * (1.f / 128.f);
    float vv2 = 0.f;
    #pragma unroll
    for (int q = 0; q < 8; ++q) { float d = vals[q] - mean; vv2 += d * d; }
    vv2 = redx16(vv2) * (1.f / 128.f);
    float rs = rsqrtf(vv2 + 1e-5f);
    #pragma unroll
    for (int q = 0; q < 8; ++q) hreg[m][q] = (vals[q] - mean) * rs * onw[col + q] + onb[col + q];
    msk[m] = tokm[row];
  }

  // ---- phase 3: surface partials + chunk means + lgu/gu ----
  __syncthreads();   // Y reads in phase 2 done; reuse Y
  float* partS = Y;               // 16*128
  float* partM = Y + 2048;        // 16*128
  float* lnus  = Y + 4096;        // 8*128
  float ps[8], pm[8];
  #pragma unroll
  for (int q = 0; q < 8; ++q) {
    ps[q] = msk[0] * hreg[0][q] + msk[1] * hreg[1][q];
    float m0 = (msk[0] != 0.f) ? hreg[0][q] : -FLT_MAX;
    float m1 = (msk[1] != 0.f) ? hreg[1][q] : -FLT_MAX;
    pm[q] = fmaxf(m0, m1);
  }
  #pragma unroll
  for (int q = 0; q < 8; ++q) { partS[tm * 128 + col + q] = ps[q]; partM[tm * 128 + col + q] = pm[q]; }

  float ccnt = msk[0] + msk[1];
  float csum[8];
  #pragma unroll
  for (int q = 0; q < 8; ++q) csum[q] = ps[q];
  #pragma unroll
  for (int q = 0; q < 8; ++q) csum[q] += __shfl_xor(csum[q], 16);
  ccnt += __shfl_xor(ccnt, 16);

  if ((tm & 1) == 0) {
    int jg = tile * 8 + (tm >> 1);
    float inv = 1.f / fmaxf(ccnt, 1.f);
    float cm[8];
    #pragma unroll
    for (int q = 0; q < 8; ++q) cm[q] = csum[q] * inv;
    *reinterpret_cast<float4*>(&chunk_h[((size_t)b * NCH + jg) * DMD + col])     = *reinterpret_cast<float4*>(&cm[0]);
    *reinterpret_cast<float4*>(&chunk_h[((size_t)b * NCH + jg) * DMD + col + 4]) = *reinterpret_cast<float4*>(&cm[4]);
    if (tn == 0) validf[jg * BB + b] = (ccnt > 0.f) ? 1.f : 0.f;
    float gp = 0.f;
    #pragma unroll
    for (int q = 0; q < 8; ++q) gp += cm[q] * wgv[col + q];
    gp = redx16(gp);
    if (tn == 0) gu[(size_t)jg * BB + b] = gp;
    float s2 = 0.f;
    #pragma unroll
    for (int q = 0; q < 8; ++q) s2 += cm[q];
    s2 = redx16(s2);
    float mean2 = s2 * (1.f / 128.f);
    float v3 = 0.f;
    #pragma unroll
    for (int q = 0; q < 8; ++q) { float d = cm[q] - mean2; v3 += d * d; }
    v3 = redx16(v3) * (1.f / 128.f);
    float rs2 = rsqrtf(v3 + 1e-5f);
    int ch = tm >> 1;
    #pragma unroll
    for (int q = 0; q < 8; ++q) lnus[ch * 128 + col + q] = (cm[q] - mean2) * rs2 * unw[col + q] + unb[col + q];
  }
  __syncthreads();
  {
    int ch = t >> 5, o = t & 31;
    float accl = 0.f;
    for (int d = 0; d < 128; ++d) accl += lnus[ch * 128 + d] * wcu[d * 32 + o];
    int jg2 = tile * 8 + ch;
    lgu[((size_t)jg2 * BB + b) * 32 + o] = accl;
  }
  if (t < 128) {
    float s3 = 0.f, m3 = -FLT_MAX;
    #pragma unroll
    for (int g = 0; g < 16; ++g) { s3 += partS[g * 128 + t]; m3 = fmaxf(m3, partM[g * 128 + t]); }
    spsum[((size_t)b * 64 + tile) * DMD + t] = s3;
    spmax[((size_t)b * 64 + tile) * DMD + t] = m3;
  }
  if (t == 128) {
    float cnt = 0.f;
    for (int r = 0; r < 32; ++r) cnt += tokm[r];
    spcnt[b * 64 + tile] = cnt;
  }
}

// ---------------- surface finalize ----------------
__global__ __launch_bounds__(128) void k_surface(
    const float* __restrict__ spsum, const float* __restrict__ spmax, const float* __restrict__ spcnt,
    float* __restrict__ smean, float* __restrict__ smax) {
  const int b = blockIdx.x, d = threadIdx.x;
  float s = 0.f, m = -FLT_MAX, cnt = 0.f;
  for (int p = 0; p < 64; ++p) {
    s += spsum[((size_t)b * 64 + p) * DMD + d];
    m = fmaxf(m, spmax[((size_t)b * 64 + p) * DMD + d]);
    cnt += spcnt[b * 64 + p];
  }
  smean[b * DMD + d] = s / fmaxf(cnt, 1.f);
  smax[b * DMD + d] = (cnt > 0.f) ? m : 0.f;
}

// ============================================================================
// k_prep_w: swizzle [wcdu;wcdc] into MFMA B-fragment order, bf16 hi/lo.
// ============================================================================
__global__ __launch_bounds__(256) void k_prep_w(
    const float* __restrict__ wcdu, const float* __restrict__ wcdc,
    unsigned short* __restrict__ Whi, unsigned short* __restrict__ Wlo) {
  int tid = blockIdx.x * 256 + threadIdx.x;     // 81920 total
  int lane = tid & 63;
  int ks = (tid >> 6) % 5;
  int nt = tid / 320;
  int col = nt * 16 + (lane & 15);
  int kbase = ks * 32 + (lane >> 4) * 8;
  F8 hi, lo;
  #pragma unroll
  for (int j = 0; j < 8; ++j) {
    int k = kbase + j;
    float wv = (k < 128) ? wcdu[(size_t)k * 4096 + col] : wcdc[(size_t)(k - 128) * 4096 + col];
    unsigned short h = f2bf(wv);
    hi.u[j] = h;
    lo.u[j] = f2bf(wv - bfbits2f(h));
  }
  *reinterpret_cast<uint4*>(Whi + (size_t)tid * 8) = hi.q;
  *reinterpret_cast<uint4*>(Wlo + (size_t)tid * 8) = lo.q;
}

// ============================================================================
// k_cand_mfma: cand = [u|c_t] @ [wcdu;wcdc] + biases via bf16x3 MFMA.
// ============================================================================
__global__ __launch_bounds__(256) void k_cand_mfma(
    const float* __restrict__ chunk_h, const float* __restrict__ c_g,
    const unsigned short* __restrict__ Whi, const unsigned short* __restrict__ Wlo,
    const float* __restrict__ bcdu, const float* __restrict__ bcdc,
    unsigned short* __restrict__ cand, int j0) {
  const int lj = blockIdx.y, j = j0 + lj;
  const int w = threadIdx.x >> 6, l = threadIdx.x & 63;
  const int nb = blockIdx.x * 256 + w * 64;
  const int l16 = l & 15, lk = l >> 4;
  f4v acc[4][4];
  #pragma unroll
  for (int mf = 0; mf < 4; ++mf)
    #pragma unroll
    for (int nf = 0; nf < 4; ++nf) acc[mf][nf] = (f4v)(0.f);
  #pragma unroll
  for (int ks = 0; ks < 5; ++ks) {
    F8 ahi[4], alo[4];
    #pragma unroll
    for (int mf = 0; mf < 4; ++mf) {
      int row = mf * 16 + l16;   // batch index
      float av[8];
      if (ks < 4) {
        const float* src = chunk_h + ((size_t)row * NCH + j) * DMD + ks * 32 + lk * 8;
        *reinterpret_cast<float4*>(&av[0]) = *reinterpret_cast<const float4*>(src);
        *reinterpret_cast<float4*>(&av[4]) = *reinterpret_cast<const float4*>(src + 4);
      } else {
        const float* src = c_g + ((size_t)j * BB + row) * 32 + lk * 8;
        *reinterpret_cast<float4*>(&av[0]) = *reinterpret_cast<const float4*>(src);
        *reinterpret_cast<float4*>(&av[4]) = *reinterpret_cast<const float4*>(src + 4);
      }
      #pragma unroll
      for (int q = 0; q < 8; ++q) {
        unsigned short h = f2bf(av[q]);
        ahi[mf].u[q] = h;
        alo[mf].u[q] = f2bf(av[q] - bfbits2f(h));
      }
    }
    #pragma unroll
    for (int nf = 0; nf < 4; ++nf) {
      int nt = (nb >> 4) + nf;
      size_t off = (((size_t)nt * 5 + ks) * 64 + l) * 8;
      F8 bhi, blo;
      bhi.q = *reinterpret_cast<const uint4*>(Whi + off);
      blo.q = *reinterpret_cast<const uint4*>(Wlo + off);
      #pragma unroll
      for (int mf = 0; mf < 4; ++mf) {
        acc[mf][nf] = __builtin_amdgcn_mfma_f32_16x16x32_bf16(ahi[mf].v, bhi.v, acc[mf][nf], 0, 0, 0);
        acc[mf][nf] = __builtin_amdgcn_mfma_f32_16x16x32_bf16(ahi[mf].v, blo.v, acc[mf][nf], 0, 0, 0);
        acc[mf][nf] = __builtin_amdgcn_mfma_f32_16x16x32_bf16(alo[mf].v, bhi.v, acc[mf][nf], 0, 0, 0);
      }
    }
  }
  #pragma unroll
  for (int nf = 0; nf < 4; ++nf) {
    int colc = nb + nf * 16 + l16;
    float bias = bcdu[colc] + bcdc[colc];
    #pragma unroll
    for (int mf = 0; mf < 4; ++mf) {
      #pragma unroll
      for (int r = 0; r < 4; ++r) {
        int row = mf * 16 + lk * 4 + r;
        cand[((size_t)lj * BB + row) * 4096 + colc] = f2bf(acc[mf][nf][r] + bias);
      }
    }
  }
}

// ============================================================================
// k_accrec: the closed (a, c) recurrence. One wave per batch.
// ============================================================================
__global__ __launch_bounds__(64) void k_accrec(
    const float* __restrict__ lgu, const float* __restrict__ gu,
    const float* __restrict__ validf,
    const float* __restrict__ wcc, const float* __restrict__ cnw, const float* __restrict__ cnb,
    const float* __restrict__ wg, const float* __restrict__ bg,
    float* __restrict__ a_g, float* __restrict__ c_g, float* __restrict__ gpart_g) {
  __shared__ float wcc_l[CDD * CDD];
  __shared__ float cn_s[CDD];
  __shared__ float as_s[CDD];
  const int t = threadIdx.x, l = t & 31;
  const int b = blockIdx.x;
  for (int i = t; i < CDD * CDD; i += 64) wcc_l[i] = wcc[i];
  __syncthreads();
  const float cw = cnw[l], cb = cnb[l], wgc = wg[DMD + l];
  const float bgs = bg[0];
  float c = 0.f;
  float lg = lgu[(size_t)b * 32 + l];
  float vld = validf[b];
  float guv = gu[b];
  for (int j = 0; j < NCH; ++j) {
    const int jn = (j + 1 < NCH) ? j + 1 : j;
    const size_t jbn = (size_t)jn * BB + b;
    float lgN = lgu[jbn * 32 + l];
    float vldN = validf[jbn];
    float guvN = gu[jbn];
    float mean = redx32(c) * (1.f / 32.f);
    float dv = c - mean;
    float var = redx32(dv * dv) * (1.f / 32.f);
    float cn = dv * rsqrtf(var + 1e-5f) * cw + cb;
    if (t < 32) cn_s[l] = cn;
    float l0 = lg, l1 = 0.f;
    #pragma unroll
    for (int i = 0; i < 16; ++i) {
      l0 += cn_s[i] * wcc_l[i * 32 + l];
      l1 += cn_s[i + 16] * wcc_l[(i + 16) * 32 + l];
    }
    float logit = l0 + l1;
    float sv = (logit > 0.05f) ? (logit - 0.05f) : ((logit < -0.05f) ? (logit + 0.05f) : 0.f);
    float as = fabsf(sv);
    if (t < 32) as_s[l] = as;
    int r0 = 0, r1 = 0;
    #pragma unroll
    for (int i = 0; i < 16; ++i) {
      float a0 = as_s[i], a1 = as_s[i + 16];
      r0 += (a0 > as || (a0 == as && i < l)) ? 1 : 0;
      r1 += (a1 > as || (a1 == as && (i + 16) < l)) ? 1 : 0;
    }
    float av = ((r0 + r1) < 8) ? sv : 0.f;
    float ct = (vld != 0.f) ? (0.9f * c + 0.1f * av) : c;
    c = ct;
    float dotc = redx32(ct * wgc);
    if (t < 32) {
      const size_t jb = (size_t)j * BB + b;
      a_g[jb * 32 + l] = av;
      c_g[jb * 32 + l] = ct;
      if (l == 0) gpart_g[jb] = guv + dotc + bgs;
    }
    lg = lgN; vld = vldN; guv = guvN;
  }
}

// ============================================================================
// k_scan_seg: D-only recurrence, 2 barriers/step, D in registers.
// ============================================================================
__global__ __launch_bounds__(512) void k_scan_seg(
    const float* __restrict__ chunk_h, const float* __restrict__ a_gg,
    const float* __restrict__ c_g, const float* __restrict__ gpart_g,
    const float* __restrict__ validf,
    const unsigned short* __restrict__ cand, int j0, int slen,
    const float* __restrict__ wg, const float* __restrict__ base_D,
    float* __restrict__ Dst,
    const float* __restrict__ smean, const float* __restrict__ smax,
    const float* __restrict__ clw, const float* __restrict__ clb,
    const float* __restrict__ f1w, const float* __restrict__ f1b,
    const float* __restrict__ f2w, const float* __restrict__ f2b,
    float* __restrict__ out) {
  __shared__ float Dl[DMD * LDW];
  __shared__ float Cl[DMD * LDW];
  __shared__ float a_l[CDD];
  __shared__ float r_l[DMD];
  __shared__ float red[8];
  __shared__ float feat[FEATN + 2];
  __shared__ float featn[FEATN + 2];
  __shared__ float h1[256];

  const int b = blockIdx.x;
  const int t = threadIdx.x;
  const int c = t >> 4;
  const int rg = t & 15;
  const bool doInit = (j0 == 0);
  const bool doHead = (j0 + slen >= NCH);
  const float wge = wg[160];

  if (doInit) {
    for (int i = t; i < DMD * CDD; i += 512) Dl[(i >> 5) * LDW + (i & 31)] = base_D[i];
  } else {
    for (int i = t; i < DMD * CDD; i += 512) Dl[(i >> 5) * LDW + (i & 31)] = Dst[(size_t)b * 4096 + i];
  }
  __syncthreads();
  float Dv[8];
  if (doInit) {
    float s = 0.f;
    #pragma unroll
    for (int m = 0; m < 8; ++m) { Dv[m] = Dl[(rg + 16 * m) * LDW + c]; s += Dv[m] * Dv[m]; }
    s = redx16(s);
    float inv = 1.f / fmaxf(sqrtf(s), 1e-12f);
    #pragma unroll
    for (int m = 0; m < 8; ++m) { Dv[m] *= inv; Dl[(rg + 16 * m) * LDW + c] = Dv[m]; }
  } else {
    #pragma unroll
    for (int m = 0; m < 8; ++m) Dv[m] = Dl[(rg + 16 * m) * LDW + c];
  }
  float pf[8];
  load_cand8(cand, ((size_t)0 * BB + b) * 4096 + (size_t)t * 8, pf);
  float un_r = (t < DMD) ? chunk_h[((size_t)b * NCH + j0) * DMD + t] : 0.f;
  float a_col = a_gg[((size_t)j0 * BB + b) * 32 + c];
  if (t < 32) a_l[t] = a_gg[((size_t)j0 * BB + b) * 32 + t];
  float gpart = gpart_g[(size_t)j0 * BB + b];
  float vld = validf[(size_t)j0 * BB + b];
  float err = 0.f, gate = 0.f;

  for (int lj = 0; lj < slen; ++lj) {
    __syncthreads(); // B1
    {
      int dd = t >> 2, cc0 = (t & 3) * 8;
      #pragma unroll
      for (int q = 0; q < 8; ++q) Cl[dd * LDW + cc0 + q] = pf[q];
    }
    if (t < DMD) {
      float uh = 0.f;
      #pragma unroll
      for (int cc = 0; cc < 32; ++cc) uh += a_l[cc] * Dl[t * LDW + cc];
      float rr = un_r - uh;
      r_l[t] = rr;
      float rp = redx64(rr * rr);
      if ((t & 63) == 0) red[t >> 6] = rp;
    }
    __syncthreads(); // B2
    err = sqrtf(red[0] + red[1]);
    gate = sigmoidf_(gpart + err * wge);
    const int ljn = (lj + 1 < slen) ? (lj + 1) : lj;
    const int jn = j0 + ljn;
    float pfN[8];
    load_cand8(cand, ((size_t)ljn * BB + b) * 4096 + (size_t)t * 8, pfN);
    float unN = (t < DMD) ? chunk_h[((size_t)b * NCH + jn) * DMD + t] : 0.f;
    float aColN = a_gg[((size_t)jn * BB + b) * 32 + c];
    float a32N = (t < 32) ? a_gg[((size_t)jn * BB + b) * 32 + t] : 0.f;
    float gpN = gpart_g[(size_t)jn * BB + b];
    float vldN = validf[(size_t)jn * BB + b];
    float dl[8], dcv[8], dn[8];
    float sl = 0.f, sc = 0.f;
    #pragma unroll
    for (int m = 0; m < 8; ++m) {
      int e = (rg + 16 * m) * LDW + c;
      dl[m] = Dv[m] + 0.03f * r_l[rg + 16 * m] * a_col;
      sl += dl[m] * dl[m];
      dcv[m] = Cl[e];
      sc += dcv[m] * dcv[m];
    }
    sl = redx16(sl); sc = redx16(sc);
    float il = 1.f / fmaxf(sqrtf(sl), 1e-12f);
    float ic = 1.f / fmaxf(sqrtf(sc), 1e-12f);
    float g1 = 1.f - gate;
    float sn = 0.f;
    #pragma unroll
    for (int m = 0; m < 8; ++m) { dn[m] = g1 * dl[m] * il + gate * dcv[m] * ic; sn += dn[m] * dn[m]; }
    sn = redx16(sn);
    float inn = 1.f / fmaxf(sqrtf(sn), 1e-12f);
    const bool vb = (vld != 0.f);
    #pragma unroll
    for (int m = 0; m < 8; ++m) {
      if (vb) Dv[m] = dn[m] * inn;
      Dl[(rg + 16 * m) * LDW + c] = Dv[m];
    }
    if (t < 32) a_l[t] = a32N;
    #pragma unroll
    for (int q = 0; q < 8; ++q) pf[q] = pfN[q];
    un_r = unN; a_col = aColN; gpart = gpN; vld = vldN;
  }
  __syncthreads();
  for (int i = t; i < 4096; i += 512) Dst[(size_t)b * 4096 + i] = Dl[(i >> 5) * LDW + (i & 31)];
  if (!doHead) return;
  if (t < 32) a_l[t] = c_g[((size_t)(NCH - 1) * BB + b) * 32 + t];
  __syncthreads();
  if (t < DMD) {
    float z = 0.f;
    #pragma unroll
    for (int cc = 0; cc < 32; ++cc) z += Dl[t * LDW + cc] * a_l[cc];
    feat[t] = z;
    feat[160 + t] = smean[b * DMD + t];
    feat[288 + t] = smax[b * DMD + t];
  }
  if (t >= 128 && t < 160) feat[t] = a_l[t - 128];
  if (t == 0) { feat[416] = err; feat[417] = gate; }
  __syncthreads();
  float fv = (t < FEATN) ? feat[t] : 0.f;
  float ws1 = redx64(fv);
  if ((t & 63) == 0) red[t >> 6] = ws1;
  __syncthreads();
  float tot = 0.f;
  #pragma unroll
  for (int w = 0; w < 8; ++w) tot += red[w];
  float mean = tot * (1.f / 418.f);
  float dvv = (t < FEATN) ? (fv - mean) : 0.f;
  float ws2 = redx64(dvv * dvv);
  __syncthreads();
  if ((t & 63) == 0) red[t >> 6] = ws2;
  __syncthreads();
  float vtot = 0.f;
  #pragma unroll
  for (int w = 0; w < 8; ++w) vtot += red[w];
  float rs = rsqrtf(vtot * (1.f / 418.f) + 1e-5f);
  if (t < FEATN) featn[t] = (fv - mean) * rs * clw[t] + clb[t];
  __syncthreads();
  if (t < 256) {
    float acc = f1b[t];
    for (int f = 0; f < FEATN; ++f) acc += featn[f] * f1w[(size_t)f * 256 + t];
    h1[t] = acc * 0.5f * (1.f + erff(acc * 0.70710678f));
  }
  __syncthreads();
  if (t < 8) {
    float acc = f2b[t];
    #pragma unroll 8
    for (int i = 0; i < 256; ++i) acc += h1[i] * f2w[i * 8 + t];
    out[b * 8 + t] = acc;
  }
}

// ---------------- launch ----------------
extern "C" void kernel_launch(void* const* d_in, const int* in_sizes, int n_in,
                              void* d_out, int out_size, void* d_ws, size_t ws_size,
                              hipStream_t stream) {
  const int*   tokens = (const int*)d_in[0];
  const float* emb    = (const float*)d_in[1];
  const float* in_w   = (const float*)d_in[2];
  const float* in_b   = (const float*)d_in[3];
  const float* c1w    = (const float*)d_in[4];
  const float* c1b    = (const float*)d_in[5];
  const float* c2w    = (const float*)d_in[6];
  const float* c2b    = (const float*)d_in[7];
  const float* op_w   = (const float*)d_in[8];
  const float* op_b   = (const float*)d_in[9];
  const float* on_w   = (const float*)d_in[10];
  const float* on_b   = (const float*)d_in[11];
  const float* base_D = (const float*)d_in[12];
  const float* wcu    = (const float*)d_in[13];
  const float* wcc    = (const float*)d_in[14];
  const float* wcdu   = (const float*)d_in[15];
  const float* bcdu   = (const float*)d_in[16];
  const float* wcdc   = (const float*)d_in[17];
  const float* bcdc   = (const float*)d_in[18];
  const float* wg     = (const float*)d_in[19];
  const float* bg     = (const float*)d_in[20];
  const float* un_w   = (const float*)d_in[21];
  const float* un_b   = (const float*)d_in[22];
  const float* cn_w   = (const float*)d_in[23];
  const float* cn_b   = (const float*)d_in[24];
  const float* cl_w   = (const float*)d_in[25];
  const float* cl_b   = (const float*)d_in[26];
  const float* f1w    = (const float*)d_in[27];
  const float* f1b    = (const float*)d_in[28];
  const float* f2w    = (const float*)d_in[29];
  const float* f2b    = (const float*)d_in[30];

  // ---- adaptive workspace layout ----
  const size_t CHEL = (size_t)BB * NCH * DMD;
  const size_t NB   = (size_t)NCH * BB;
  size_t fixedFloats = CHEL + NB + NB * 32 + NB
                     + (size_t)BB * 64 * DMD * 2 + (size_t)BB * 64
                     + (size_t)BB * DMD * 2 + (size_t)BB * 4096
                     + NB * 32 + NB * 32 + NB;
  const size_t WFRAG  = 655360ull;                      // cand-weight ushorts per copy
  const size_t W3FR   = 98304ull;                       // conv3 frag ushorts per copy
  const size_t W5FR   = 163840ull;                      // conv5 frag ushorts per copy
  const size_t WSWZ_BYTES = (2ull * WFRAG + 2ull * W3FR + 2ull * W5FR) * 2ull;
  const size_t FIXED_BYTES = fixedFloats * 4 + WSWZ_BYTES;
  const size_t SEG_UNIT = (size_t)BB * 4096 * 2;        // 512 KB per step
  int S = 512;
  while (S > 1 && (size_t)S * SEG_UNIT + FIXED_BYTES > ws_size) S >>= 1;

  unsigned short* cand = (unsigned short*)d_ws;
  unsigned short* Whi  = (unsigned short*)((char*)d_ws + (size_t)S * SEG_UNIT);
  unsigned short* Wlo  = Whi + WFRAG;
  unsigned short* W3hi = Wlo + WFRAG;
  unsigned short* W3lo = W3hi + W3FR;
  unsigned short* W5hi = W3lo + W3FR;
  unsigned short* W5lo = W5hi + W5FR;
  float* base = (float*)(W5lo + W5FR);
  float* chunk_h = base; base += CHEL;
  float* validf  = base; base += NB;
  float* lgu     = base; base += NB * 32;
  float* gu      = base; base += NB;
  float* spsum   = base; base += (size_t)BB * 64 * DMD;
  float* spmax   = base; base += (size_t)BB * 64 * DMD;
  float* spcnt   = base; base += (size_t)BB * 64;
  float* smean   = base; base += (size_t)BB * DMD;
  float* smaxv   = base; base += (size_t)BB * DMD;
  float* Dst     = base; base += (size_t)BB * 4096;
  float* a_g     = base; base += NB * 32;
  float* c_g     = base; base += NB * 32;
  float* gpart   = base; base += NB;
  float* out = (float*)d_out;
  fprintf(stderr, "[hsfc69] ws_size=%zu fixed=%zu S=%d total=%zu\n",
          ws_size, FIXED_BYTES, S, FIXED_BYTES + (size_t)S * SEG_UNIT);

  k_prep_w<<<dim3(320), dim3(256), 0, stream>>>(wcdu, wcdc, Whi, Wlo);
  k_prep_conv<<<dim3(128), dim3(256), 0, stream>>>(c1w, c2w, W3hi, W3lo, W5hi, W5lo);
  k_front<<<dim3(64, BB), dim3(256), 0, stream>>>(
      tokens, emb, in_w, in_b, W3hi, W3lo, W5hi, W5lo, c1b, c2b,
      op_w, op_b, on_w, on_b, un_w, un_b, wcu, wg,
      chunk_h, validf, lgu, gu, spsum, spmax, spcnt);
  k_surface<<<dim3(BB), dim3(128), 0, stream>>>(spsum, spmax, spcnt, smean, smaxv);
  k_accrec<<<dim3(BB), dim3(64), 0, stream>>>(
      lgu, gu, validf, wcc, cn_w, cn_b, wg, bg, a_g, c_g, gpart);
  for (int j0 = 0; j0 < NCH; j0 += S) {
    k_cand_mfma<<<dim3(16, S), dim3(256), 0, stream>>>(
        chunk_h, c_g, Whi, Wlo, bcdu, bcdc, cand, j0);
    k_scan_seg<<<dim3(BB), dim3(512), 0, stream>>>(
        chunk_h, a_g, c_g, gpart, validf, cand, j0, S,
        wg, base_D, Dst, smean, smaxv, cl_w, cl_b, f1w, f1b, f2w, f2b, out);
  }
}

// Round 7
// 2937.324 us; speedup vs baseline: 4.0096x; 1.0197x over previous
//
#include <hip/hip_runtime.h>
#include <hip/hip_bf16.h>
#include <cfloat>
#include <cstdio>

#define TT   2048
#define BB   64
#define DMD  128
#define CDD  32
#define NCH  512
#define FEATN 418
#define APITCH 132  // front A-tile pitch (mult of 4 for aligned float4)
#define YPITCH 257  // front Y-tile pitch

// injective bank-spreading swizzle for op weight staging (8-float chunks)
#define WOFF2(kc,c) ((kc)*144 + (c)*8 + (((c)>>2)<<2))

// scan Dl swizzle: element position of (col c, row dd) within row dd.
// Row-reads (u_hat): quad sq = (qs + dd + (dd>>3)) & 7 holds c-group qs.
// Column-writes (D-update): 2-way bank aliasing only (free per m136).
#define DSWZ(c,dd) ((((((c)>>2) + (dd) + ((dd)>>3)) & 7) << 2) + ((c)&3))

// ---------------- helpers ----------------
__device__ __forceinline__ float redx16(float v) {
  v += __shfl_xor(v, 1); v += __shfl_xor(v, 2);
  v += __shfl_xor(v, 4); v += __shfl_xor(v, 8);
  return v;
}
__device__ __forceinline__ float redx32(float v) { v = redx16(v); v += __shfl_xor(v, 16); return v; }
__device__ __forceinline__ float redx64(float v) { v = redx32(v); v += __shfl_xor(v, 32); return v; }
__device__ __forceinline__ float bfbits2f(unsigned int u) {
  union { unsigned int i; float f; } v; v.i = u << 16; return v.f;
}
__device__ __forceinline__ unsigned short f2bf(float f) {
  union { float f; unsigned int i; } u; u.f = f;
  unsigned int r = u.i + 0x7FFFu + ((u.i >> 16) & 1u);
  return (unsigned short)(r >> 16);
}
__device__ __forceinline__ float sigmoidf_(float x) { return 1.f / (1.f + expf(-x)); }

__device__ __forceinline__ void load_cand8(const unsigned short* cand, size_t idx, float* pf) {
  uint4 v = *reinterpret_cast<const uint4*>(cand + idx);
  pf[0] = bfbits2f(v.x & 0xFFFFu); pf[1] = bfbits2f(v.x >> 16);
  pf[2] = bfbits2f(v.y & 0xFFFFu); pf[3] = bfbits2f(v.y >> 16);
  pf[4] = bfbits2f(v.z & 0xFFFFu); pf[5] = bfbits2f(v.z >> 16);
  pf[6] = bfbits2f(v.w & 0xFFFFu); pf[7] = bfbits2f(v.w >> 16);
}

typedef __attribute__((ext_vector_type(8))) short s8v;
typedef __attribute__((ext_vector_type(4))) float f4v;
union F8 { s8v v; unsigned short u[8]; uint4 q; };

// ============================================================================
// k_prep_conv: swizzle conv weights into MFMA B-fragment lane order (hi/lo).
// ============================================================================
__global__ __launch_bounds__(256) void k_prep_conv(
    const float* __restrict__ c1w, const float* __restrict__ c2w,
    unsigned short* __restrict__ W3hi, unsigned short* __restrict__ W3lo,
    unsigned short* __restrict__ W5hi, unsigned short* __restrict__ W5lo) {
  int tid = blockIdx.x * 256 + threadIdx.x;   // 32768 total
  const float* src; unsigned short *dh, *dl; int fid;
  if (tid < 12288) { fid = tid;        src = c1w; dh = W3hi; dl = W3lo; }
  else             { fid = tid - 12288; src = c2w; dh = W5hi; dl = W5lo; }
  int lane = fid & 63;
  int nt   = (fid >> 6) & 15;
  int kc   = (fid >> 10) & 3;
  int tap  = fid >> 12;
  int col  = nt * 16 + (lane & 15);
  int kb   = tap * 128 + kc * 32 + (lane >> 4) * 8;
  F8 hi, lo;
  #pragma unroll
  for (int j = 0; j < 8; ++j) {
    float wv = src[(size_t)(kb + j) * 256 + col];
    unsigned short h = f2bf(wv);
    hi.u[j] = h;
    lo.u[j] = f2bf(wv - bfbits2f(h));
  }
  *reinterpret_cast<uint4*>(dh + (size_t)fid * 8) = hi.q;
  *reinterpret_cast<uint4*>(dl + (size_t)fid * 8) = lo.q;
}

// ============================================================================
// k_front: embed+LN -> conv3/5 bf16x4 MFMA + GLU -> op GEMM + residual + LN ->
// chunk means, surface partials, lgu/gu.  (unchanged from round 6)
// ============================================================================
__global__ __launch_bounds__(256) void k_front(
    const int* __restrict__ tokens, const float* __restrict__ emb,
    const float* __restrict__ inw, const float* __restrict__ inb,
    const unsigned short* __restrict__ W3hi, const unsigned short* __restrict__ W3lo,
    const unsigned short* __restrict__ W5hi, const unsigned short* __restrict__ W5lo,
    const float* __restrict__ c1b, const float* __restrict__ c2b,
    const float* __restrict__ opw, const float* __restrict__ opb,
    const float* __restrict__ onw, const float* __restrict__ onb,
    const float* __restrict__ unw, const float* __restrict__ unb,
    const float* __restrict__ wcu, const float* __restrict__ wgv,
    float* __restrict__ chunk_h, float* __restrict__ validf,
    float* __restrict__ lgu, float* __restrict__ gu,
    float* __restrict__ spsum, float* __restrict__ spmax, float* __restrict__ spcnt) {
  __shared__ float A[36 * APITCH];
  __shared__ float Y[32 * YPITCH];
  __shared__ float ABf[4608];
  __shared__ float tokm[32];
  unsigned short* Ahi = (unsigned short*)ABf;
  unsigned short* Alo = Ahi + 36 * 128;
  const int b = blockIdx.y, tile = blockIdx.x;
  const int t0 = tile * 32;
  const int t = threadIdx.x;
  const int lane = t & 63, wq = t >> 6;

  for (int r = wq; r < 36; r += 4) {
    int p = t0 + r - 2;
    float2 o = make_float2(0.f, 0.f);
    if (p >= 0 && p < TT) {
      int tok = tokens[b * TT + p];
      if (lane == 0 && r >= 2 && r < 34) tokm[r - 2] = (tok != 0) ? 1.f : 0.f;
      float2 e = *reinterpret_cast<const float2*>(emb + (size_t)tok * DMD + lane * 2);
      float mean = redx64(e.x + e.y) * (1.f / 128.f);
      float d0 = e.x - mean, d1 = e.y - mean;
      float vvv = redx64(d0 * d0 + d1 * d1) * (1.f / 128.f);
      float rs = rsqrtf(vvv + 1e-5f);
      o.x = d0 * rs * inw[lane * 2]     + inb[lane * 2];
      o.y = d1 * rs * inw[lane * 2 + 1] + inb[lane * 2 + 1];
    }
    *reinterpret_cast<float2*>(&A[r * APITCH + lane * 2]) = o;
    unsigned short hx = f2bf(o.x), hy = f2bf(o.y);
    unsigned short lx = f2bf(o.x - bfbits2f(hx)), ly = f2bf(o.y - bfbits2f(hy));
    int slot = (lane >> 2) ^ (r & 7);
    int ui = r * 64 + slot * 4 + (lane & 3);
    ((unsigned int*)Ahi)[ui] = (unsigned int)hx | ((unsigned int)hy << 16);
    ((unsigned int*)Alo)[ui] = (unsigned int)lx | ((unsigned int)ly << 16);
  }
  __syncthreads();

  const int l16 = lane & 15, lk = lane >> 4;
  f4v acc3[2][4], acc5[2][4];
  #pragma unroll
  for (int mt = 0; mt < 2; ++mt)
    #pragma unroll
    for (int nf = 0; nf < 4; ++nf) { acc3[mt][nf] = (f4v)(0.f); acc5[mt][nf] = (f4v)(0.f); }
  #pragma unroll
  for (int d = 0; d < 5; ++d) {
    #pragma unroll
    for (int kc = 0; kc < 4; ++kc) {
      F8 ahi[2], alo[2];
      #pragma unroll
      for (int mt = 0; mt < 2; ++mt) {
        int arow = mt * 16 + l16 + d;
        int s = (kc * 4 + lk) ^ (arow & 7);
        ahi[mt].q = *reinterpret_cast<const uint4*>(Ahi + arow * 128 + s * 8);
        alo[mt].q = *reinterpret_cast<const uint4*>(Alo + arow * 128 + s * 8);
      }
      #pragma unroll
      for (int nf = 0; nf < 4; ++nf) {
        int nt = (nf < 2) ? (wq * 2 + nf) : (8 + wq * 2 + nf - 2);
        size_t off = ((size_t)((d * 4 + kc) * 16 + nt) * 64 + lane) * 8;
        F8 bh, bl;
        bh.q = *reinterpret_cast<const uint4*>(W5hi + off);
        bl.q = *reinterpret_cast<const uint4*>(W5lo + off);
        #pragma unroll
        for (int mt = 0; mt < 2; ++mt) {
          acc5[mt][nf] = __builtin_amdgcn_mfma_f32_16x16x32_bf16(ahi[mt].v, bh.v, acc5[mt][nf], 0, 0, 0);
          acc5[mt][nf] = __builtin_amdgcn_mfma_f32_16x16x32_bf16(ahi[mt].v, bl.v, acc5[mt][nf], 0, 0, 0);
          acc5[mt][nf] = __builtin_amdgcn_mfma_f32_16x16x32_bf16(alo[mt].v, bh.v, acc5[mt][nf], 0, 0, 0);
          acc5[mt][nf] = __builtin_amdgcn_mfma_f32_16x16x32_bf16(alo[mt].v, bl.v, acc5[mt][nf], 0, 0, 0);
        }
      }
      if (d >= 1 && d <= 3) {
        int tap = d - 1;
        #pragma unroll
        for (int nf = 0; nf < 4; ++nf) {
          int nt = (nf < 2) ? (wq * 2 + nf) : (8 + wq * 2 + nf - 2);
          size_t off = ((size_t)((tap * 4 + kc) * 16 + nt) * 64 + lane) * 8;
          F8 bh, bl;
          bh.q = *reinterpret_cast<const uint4*>(W3hi + off);
          bl.q = *reinterpret_cast<const uint4*>(W3lo + off);
          #pragma unroll
          for (int mt = 0; mt < 2; ++mt) {
            acc3[mt][nf] = __builtin_amdgcn_mfma_f32_16x16x32_bf16(ahi[mt].v, bh.v, acc3[mt][nf], 0, 0, 0);
            acc3[mt][nf] = __builtin_amdgcn_mfma_f32_16x16x32_bf16(ahi[mt].v, bl.v, acc3[mt][nf], 0, 0, 0);
            acc3[mt][nf] = __builtin_amdgcn_mfma_f32_16x16x32_bf16(alo[mt].v, bh.v, acc3[mt][nf], 0, 0, 0);
            acc3[mt][nf] = __builtin_amdgcn_mfma_f32_16x16x32_bf16(alo[mt].v, bl.v, acc3[mt][nf], 0, 0, 0);
          }
        }
      }
    }
  }
  #pragma unroll
  for (int mt = 0; mt < 2; ++mt)
    #pragma unroll
    for (int nf = 0; nf < 2; ++nf) {
      int col = wq * 32 + nf * 16 + l16;
      #pragma unroll
      for (int r = 0; r < 4; ++r) {
        int row = mt * 16 + lk * 4 + r;
        float av3 = acc3[mt][nf][r]     + c1b[col];
        float gv3 = acc3[mt][nf + 2][r] + c1b[128 + col];
        Y[row * YPITCH + col] = av3 * sigmoidf_(gv3);
        float av5 = acc5[mt][nf][r]     + c2b[col];
        float gv5 = acc5[mt][nf + 2][r] + c2b[128 + col];
        Y[row * YPITCH + 128 + col] = av5 * sigmoidf_(gv5);
      }
    }
  __syncthreads();

  const int tm = t >> 4, tn = t & 15;
  const int r0 = tm * 2;
  float* Wl = ABf;
  float acc2[2][8] = {};
  {
    const int kcw = t >> 4, cw2 = t & 15;
    {
      float4 wr0 = *reinterpret_cast<const float4*>(&opw[(size_t)kcw * 128 + cw2 * 8]);
      float4 wr1 = *reinterpret_cast<const float4*>(&opw[(size_t)kcw * 128 + cw2 * 8 + 4]);
      *reinterpret_cast<float4*>(&Wl[WOFF2(kcw, cw2)])     = wr0;
      *reinterpret_cast<float4*>(&Wl[WOFF2(kcw, cw2) + 4]) = wr1;
    }
    __syncthreads();
    for (int k0 = 0; k0 < 256; k0 += 16) {
      float* Wb = Wl + (((k0 >> 4) & 1) ? 2304 : 0);
      const bool more = (k0 + 16) < 256;
      float4 nr0, nr1;
      if (more) {
        nr0 = *reinterpret_cast<const float4*>(&opw[(size_t)(k0 + 16 + kcw) * 128 + cw2 * 8]);
        nr1 = *reinterpret_cast<const float4*>(&opw[(size_t)(k0 + 16 + kcw) * 128 + cw2 * 8 + 4]);
      }
      #pragma unroll
      for (int kc = 0; kc < 16; ++kc) {
        int k = k0 + kc;
        float y0 = Y[r0 * YPITCH + k];
        float y1 = Y[(r0 + 1) * YPITCH + k];
        float w8[8];
        *reinterpret_cast<float4*>(&w8[0]) = *reinterpret_cast<float4*>(&Wb[WOFF2(kc, tn)]);
        *reinterpret_cast<float4*>(&w8[4]) = *reinterpret_cast<float4*>(&Wb[WOFF2(kc, tn) + 4]);
        #pragma unroll
        for (int q = 0; q < 8; ++q) { acc2[0][q] += y0 * w8[q]; acc2[1][q] += y1 * w8[q]; }
      }
      if (more) {
        float* Wn = Wl + ((((k0 >> 4) + 1) & 1) ? 2304 : 0);
        *reinterpret_cast<float4*>(&Wn[WOFF2(kcw, cw2)])     = nr0;
        *reinterpret_cast<float4*>(&Wn[WOFF2(kcw, cw2) + 4]) = nr1;
      }
      __syncthreads();
    }
  }

  const int col = tn * 8;
  float hreg[2][8];
  float msk[2];
  #pragma unroll
  for (int m = 0; m < 2; ++m) {
    int row = r0 + m;
    float vals[8]; float s = 0.f;
    const float* xr = &A[(row + 2) * APITCH + col];
    #pragma unroll
    for (int q = 0; q < 8; ++q) { vals[q] = acc2[m][q] + opb[col + q] + xr[q]; s += vals[q]; }
    s = redx16(s);
    float mean = s * (1.f / 128.f);
    float vv2 = 0.f;
    #pragma unroll
    for (int q = 0; q < 8; ++q) { float d = vals[q] - mean; vv2 += d * d; }
    vv2 = redx16(vv2) * (1.f / 128.f);
    float rs = rsqrtf(vv2 + 1e-5f);
    #pragma unroll
    for (int q = 0; q < 8; ++q) hreg[m][q] = (vals[q] - mean) * rs * onw[col + q] + onb[col + q];
    msk[m] = tokm[row];
  }

  __syncthreads();
  float* partS = Y;
  float* partM = Y + 2048;
  float* lnus  = Y + 4096;
  float ps[8], pm[8];
  #pragma unroll
  for (int q = 0; q < 8; ++q) {
    ps[q] = msk[0] * hreg[0][q] + msk[1] * hreg[1][q];
    float m0 = (msk[0] != 0.f) ? hreg[0][q] : -FLT_MAX;
    float m1 = (msk[1] != 0.f) ? hreg[1][q] : -FLT_MAX;
    pm[q] = fmaxf(m0, m1);
  }
  #pragma unroll
  for (int q = 0; q < 8; ++q) { partS[tm * 128 + col + q] = ps[q]; partM[tm * 128 + col + q] = pm[q]; }

  float ccnt = msk[0] + msk[1];
  float csum[8];
  #pragma unroll
  for (int q = 0; q < 8; ++q) csum[q] = ps[q];
  #pragma unroll
  for (int q = 0; q < 8; ++q) csum[q] += __shfl_xor(csum[q], 16);
  ccnt += __shfl_xor(ccnt, 16);

  if ((tm & 1) == 0) {
    int jg = tile * 8 + (tm >> 1);
    float inv = 1.f / fmaxf(ccnt, 1.f);
    float cm[8];
    #pragma unroll
    for (int q = 0; q < 8; ++q) cm[q] = csum[q] * inv;
    *reinterpret_cast<float4*>(&chunk_h[((size_t)b * NCH + jg) * DMD + col])     = *reinterpret_cast<float4*>(&cm[0]);
    *reinterpret_cast<float4*>(&chunk_h[((size_t)b * NCH + jg) * DMD + col + 4]) = *reinterpret_cast<float4*>(&cm[4]);
    if (tn == 0) validf[jg * BB + b] = (ccnt > 0.f) ? 1.f : 0.f;
    float gp = 0.f;
    #pragma unroll
    for (int q = 0; q < 8; ++q) gp += cm[q] * wgv[col + q];
    gp = redx16(gp);
    if (tn == 0) gu[(size_t)jg * BB + b] = gp;
    float s2 = 0.f;
    #pragma unroll
    for (int q = 0; q < 8; ++q) s2 += cm[q];
    s2 = redx16(s2);
    float mean2 = s2 * (1.f / 128.f);
    float v3 = 0.f;
    #pragma unroll
    for (int q = 0; q < 8; ++q) { float d = cm[q] - mean2; v3 += d * d; }
    v3 = redx16(v3) * (1.f / 128.f);
    float rs2 = rsqrtf(v3 + 1e-5f);
    int ch = tm >> 1;
    #pragma unroll
    for (int q = 0; q < 8; ++q) lnus[ch * 128 + col + q] = (cm[q] - mean2) * rs2 * unw[col + q] + unb[col + q];
  }
  __syncthreads();
  {
    int ch = t >> 5, o = t & 31;
    float accl = 0.f;
    for (int d = 0; d < 128; ++d) accl += lnus[ch * 128 + d] * wcu[d * 32 + o];
    int jg2 = tile * 8 + ch;
    lgu[((size_t)jg2 * BB + b) * 32 + o] = accl;
  }
  if (t < 128) {
    float s3 = 0.f, m3 = -FLT_MAX;
    #pragma unroll
    for (int g = 0; g < 16; ++g) { s3 += partS[g * 128 + t]; m3 = fmaxf(m3, partM[g * 128 + t]); }
    spsum[((size_t)b * 64 + tile) * DMD + t] = s3;
    spmax[((size_t)b * 64 + tile) * DMD + t] = m3;
  }
  if (t == 128) {
    float cnt = 0.f;
    for (int r = 0; r < 32; ++r) cnt += tokm[r];
    spcnt[b * 64 + tile] = cnt;
  }
}

// ---------------- surface finalize ----------------
__global__ __launch_bounds__(128) void k_surface(
    const float* __restrict__ spsum, const float* __restrict__ spmax, const float* __restrict__ spcnt,
    float* __restrict__ smean, float* __restrict__ smax) {
  const int b = blockIdx.x, d = threadIdx.x;
  float s = 0.f, m = -FLT_MAX, cnt = 0.f;
  for (int p = 0; p < 64; ++p) {
    s += spsum[((size_t)b * 64 + p) * DMD + d];
    m = fmaxf(m, spmax[((size_t)b * 64 + p) * DMD + d]);
    cnt += spcnt[b * 64 + p];
  }
  smean[b * DMD + d] = s / fmaxf(cnt, 1.f);
  smax[b * DMD + d] = (cnt > 0.f) ? m : 0.f;
}

// ============================================================================
// k_prep_w: [wcdu;wcdc] -> MFMA B-fragments ordered per (c, dd-tile, ks).
// frag f = (c*8 + ddt)*5 + ks; lane l: col = (ddt*16 + (l&15))*32 + c,
// k = ks*32 + (l>>4)*8 + j.  (for the transposed-cand k_cand_mfma)
// ============================================================================
__global__ __launch_bounds__(256) void k_prep_w(
    const float* __restrict__ wcdu, const float* __restrict__ wcdc,
    unsigned short* __restrict__ Whi, unsigned short* __restrict__ Wlo) {
  int tid = blockIdx.x * 256 + threadIdx.x;     // 81920 total
  int l = tid & 63;
  int f = tid >> 6;
  int ks = f % 5;
  int ddt = (f / 5) & 7;
  int c = f / 40;
  int colc = (ddt * 16 + (l & 15)) * 32 + c;
  int kbase = ks * 32 + (l >> 4) * 8;
  F8 hi, lo;
  #pragma unroll
  for (int j = 0; j < 8; ++j) {
    int k = kbase + j;
    float wv = (k < 128) ? wcdu[(size_t)k * 4096 + colc] : wcdc[(size_t)(k - 128) * 4096 + colc];
    unsigned short h = f2bf(wv);
    hi.u[j] = h;
    lo.u[j] = f2bf(wv - bfbits2f(h));
  }
  *reinterpret_cast<uint4*>(Whi + (size_t)tid * 8) = hi.q;
  *reinterpret_cast<uint4*>(Wlo + (size_t)tid * 8) = lo.q;
}

// ============================================================================
// k_cand_mfma: cand = [u|c_t] @ [wcdu;wcdc] + biases (bf16x3 MFMA), output in
// TRANSPOSED layout cand[(lj*64+b)*4096 + c*128 + dd] via LDS-staged transpose.
// Block bx: c-pair {2bx, 2bx+1}; wave w: c = 2bx+(w&1), dd in [(w>>1)*64, +64).
// ============================================================================
__global__ __launch_bounds__(256) void k_cand_mfma(
    const float* __restrict__ chunk_h, const float* __restrict__ c_g,
    const unsigned short* __restrict__ Whi, const unsigned short* __restrict__ Wlo,
    const float* __restrict__ bcdu, const float* __restrict__ bcdc,
    unsigned short* __restrict__ cand, int j0) {
  __shared__ unsigned short stg[4 * 64 * 72];   // 36864 B, pitch 72 (conflict-spread)
  const int lj = blockIdx.y, j = j0 + lj;
  const int bx = blockIdx.x;
  const int w = threadIdx.x >> 6, l = threadIdx.x & 63;
  const int c = bx * 2 + (w & 1);
  const int ddw = (w >> 1) * 64;
  const int l16 = l & 15, lk = l >> 4;
  f4v acc[4][4];
  #pragma unroll
  for (int mf = 0; mf < 4; ++mf)
    #pragma unroll
    for (int nf = 0; nf < 4; ++nf) acc[mf][nf] = (f4v)(0.f);
  #pragma unroll
  for (int ks = 0; ks < 5; ++ks) {
    F8 ahi[4], alo[4];
    #pragma unroll
    for (int mf = 0; mf < 4; ++mf) {
      int row = mf * 16 + l16;   // batch index
      float av[8];
      if (ks < 4) {
        const float* src = chunk_h + ((size_t)row * NCH + j) * DMD + ks * 32 + lk * 8;
        *reinterpret_cast<float4*>(&av[0]) = *reinterpret_cast<const float4*>(src);
        *reinterpret_cast<float4*>(&av[4]) = *reinterpret_cast<const float4*>(src + 4);
      } else {
        const float* src = c_g + ((size_t)j * BB + row) * 32 + lk * 8;
        *reinterpret_cast<float4*>(&av[0]) = *reinterpret_cast<const float4*>(src);
        *reinterpret_cast<float4*>(&av[4]) = *reinterpret_cast<const float4*>(src + 4);
      }
      #pragma unroll
      for (int q = 0; q < 8; ++q) {
        unsigned short h = f2bf(av[q]);
        ahi[mf].u[q] = h;
        alo[mf].u[q] = f2bf(av[q] - bfbits2f(h));
      }
    }
    #pragma unroll
    for (int nf = 0; nf < 4; ++nf) {
      int ddt = (ddw >> 4) + nf;        // global 16-dd tile 0..7
      size_t off = (((size_t)(c * 8 + ddt) * 5 + ks) * 64 + l) * 8;
      F8 bhi, blo;
      bhi.q = *reinterpret_cast<const uint4*>(Whi + off);
      blo.q = *reinterpret_cast<const uint4*>(Wlo + off);
      #pragma unroll
      for (int mf = 0; mf < 4; ++mf) {
        acc[mf][nf] = __builtin_amdgcn_mfma_f32_16x16x32_bf16(ahi[mf].v, bhi.v, acc[mf][nf], 0, 0, 0);
        acc[mf][nf] = __builtin_amdgcn_mfma_f32_16x16x32_bf16(ahi[mf].v, blo.v, acc[mf][nf], 0, 0, 0);
        acc[mf][nf] = __builtin_amdgcn_mfma_f32_16x16x32_bf16(alo[mf].v, bhi.v, acc[mf][nf], 0, 0, 0);
      }
    }
  }
  // epilogue -> LDS stage (bf16)
  #pragma unroll
  for (int nf = 0; nf < 4; ++nf) {
    int dd = ddw + nf * 16 + l16;
    int colc = dd * 32 + c;
    float bias = bcdu[colc] + bcdc[colc];
    #pragma unroll
    for (int mf = 0; mf < 4; ++mf) {
      #pragma unroll
      for (int r = 0; r < 4; ++r) {
        int bb2 = mf * 16 + lk * 4 + r;
        stg[w * 4608 + bb2 * 72 + nf * 16 + l16] = f2bf(acc[mf][nf][r] + bias);
      }
    }
  }
  __syncthreads();
  // transpose-out: 16B contiguous chunks, coalesced 128B runs
  #pragma unroll
  for (int k = 0; k < 8; ++k) {
    int cid = k * 256 + threadIdx.x;
    int rw = cid >> 9;
    int rem = cid & 511;
    int bb2 = rem >> 3;
    int dd0 = (rem & 7) * 8;
    int c_r = bx * 2 + (rw & 1);
    int ddb = (rw >> 1) * 64;
    uint4 v = *reinterpret_cast<const uint4*>(&stg[rw * 4608 + bb2 * 72 + dd0]);
    *reinterpret_cast<uint4*>(&cand[((size_t)lj * BB + bb2) * 4096 + c_r * 128 + ddb + dd0]) = v;
  }
}

// ============================================================================
// k_accrec: the closed (a, c) recurrence. One wave per batch. (unchanged)
// ============================================================================
__global__ __launch_bounds__(64) void k_accrec(
    const float* __restrict__ lgu, const float* __restrict__ gu,
    const float* __restrict__ validf,
    const float* __restrict__ wcc, const float* __restrict__ cnw, const float* __restrict__ cnb,
    const float* __restrict__ wg, const float* __restrict__ bg,
    float* __restrict__ a_g, float* __restrict__ c_g, float* __restrict__ gpart_g) {
  __shared__ float wcc_l[CDD * CDD];
  __shared__ float cn_s[CDD];
  __shared__ float as_s[CDD];
  const int t = threadIdx.x, l = t & 31;
  const int b = blockIdx.x;
  for (int i = t; i < CDD * CDD; i += 64) wcc_l[i] = wcc[i];
  __syncthreads();
  const float cw = cnw[l], cb = cnb[l], wgc = wg[DMD + l];
  const float bgs = bg[0];
  float c = 0.f;
  float lg = lgu[(size_t)b * 32 + l];
  float vld = validf[b];
  float guv = gu[b];
  for (int j = 0; j < NCH; ++j) {
    const int jn = (j + 1 < NCH) ? j + 1 : j;
    const size_t jbn = (size_t)jn * BB + b;
    float lgN = lgu[jbn * 32 + l];
    float vldN = validf[jbn];
    float guvN = gu[jbn];
    float mean = redx32(c) * (1.f / 32.f);
    float dv = c - mean;
    float var = redx32(dv * dv) * (1.f / 32.f);
    float cn = dv * rsqrtf(var + 1e-5f) * cw + cb;
    if (t < 32) cn_s[l] = cn;
    float l0 = lg, l1 = 0.f;
    #pragma unroll
    for (int i = 0; i < 16; ++i) {
      l0 += cn_s[i] * wcc_l[i * 32 + l];
      l1 += cn_s[i + 16] * wcc_l[(i + 16) * 32 + l];
    }
    float logit = l0 + l1;
    float sv = (logit > 0.05f) ? (logit - 0.05f) : ((logit < -0.05f) ? (logit + 0.05f) : 0.f);
    float as = fabsf(sv);
    if (t < 32) as_s[l] = as;
    int r0 = 0, r1 = 0;
    #pragma unroll
    for (int i = 0; i < 16; ++i) {
      float a0 = as_s[i], a1 = as_s[i + 16];
      r0 += (a0 > as || (a0 == as && i < l)) ? 1 : 0;
      r1 += (a1 > as || (a1 == as && (i + 16) < l)) ? 1 : 0;
    }
    float av = ((r0 + r1) < 8) ? sv : 0.f;
    float ct = (vld != 0.f) ? (0.9f * c + 0.1f * av) : c;
    c = ct;
    float dotc = redx32(ct * wgc);
    if (t < 32) {
      const size_t jb = (size_t)j * BB + b;
      a_g[jb * 32 + l] = av;
      c_g[jb * 32 + l] = ct;
      if (l == 0) gpart_g[jb] = guv + dotc + bgs;
    }
    lg = lgN; vld = vldN; guv = guvN;
  }
}

// ============================================================================
// k_scan_seg: D-only recurrence. New layout: thread (c=t>>4, rb=t&15) owns
// D rows rb*8..rb*8+8 of column c in registers; Dl pitch-32 with DSWZ swizzle
// (aligned b128 row-reads, 2-way column-writes); cand read straight into the
// registers the D-update consumes (transposed cand layout) — no Cl tile.
// ============================================================================
__global__ __launch_bounds__(512) void k_scan_seg(
    const float* __restrict__ chunk_h, const float* __restrict__ a_gg,
    const float* __restrict__ c_g, const float* __restrict__ gpart_g,
    const float* __restrict__ validf,
    const unsigned short* __restrict__ cand, int j0, int slen,
    const float* __restrict__ wg, const float* __restrict__ base_D,
    float* __restrict__ Dst,
    const float* __restrict__ smean, const float* __restrict__ smax,
    const float* __restrict__ clw, const float* __restrict__ clb,
    const float* __restrict__ f1w, const float* __restrict__ f1b,
    const float* __restrict__ f2w, const float* __restrict__ f2b,
    float* __restrict__ out) {
  __shared__ float Dl[DMD * 32];
  __shared__ float a_l[CDD];
  __shared__ float r_l[DMD];
  __shared__ float red[8];
  __shared__ float feat[FEATN + 2];
  __shared__ float featn[FEATN + 2];
  __shared__ float h1[256];

  const int b = blockIdx.x;
  const int t = threadIdx.x;
  const int c = t >> 4;     // column 0..31
  const int rb = t & 15;    // owns rows rb*8 .. rb*8+8
  const bool doInit = (j0 == 0);
  const bool doHead = (j0 + slen >= NCH);
  const float wge = wg[160];

  // load D state into registers (rows rb*8+i, col c)
  float Dv[8];
  #pragma unroll
  for (int i = 0; i < 8; ++i) {
    int dd = rb * 8 + i;
    Dv[i] = doInit ? base_D[dd * 32 + c] : Dst[(size_t)b * 4096 + dd * 32 + c];
  }
  if (doInit) {
    float s = 0.f;
    #pragma unroll
    for (int i = 0; i < 8; ++i) s += Dv[i] * Dv[i];
    s = redx16(s);
    float inv = 1.f / fmaxf(sqrtf(s), 1e-12f);
    #pragma unroll
    for (int i = 0; i < 8; ++i) Dv[i] *= inv;
  }
  #pragma unroll
  for (int i = 0; i < 8; ++i) {
    int dd = rb * 8 + i;
    Dl[dd * 32 + DSWZ(c, dd)] = Dv[i];
  }

  // prologue prefetch for first step (transposed cand: pf = D-update's dcv)
  float pf[8];
  load_cand8(cand, ((size_t)0 * BB + b) * 4096 + (size_t)c * 128 + rb * 8, pf);
  float un_r = (t < DMD) ? chunk_h[((size_t)b * NCH + j0) * DMD + t] : 0.f;
  float a_col = a_gg[((size_t)j0 * BB + b) * 32 + c];
  if (t < 32) a_l[t] = a_gg[((size_t)j0 * BB + b) * 32 + t];
  float gpart = gpart_g[(size_t)j0 * BB + b];
  float vld = validf[(size_t)j0 * BB + b];
  float err = 0.f, gate = 0.f;

  for (int lj = 0; lj < slen; ++lj) {
    __syncthreads(); // B1: prev Dl writes + a_l visible
    if (t < DMD) {
      const int r = t;
      float uh = 0.f;
      #pragma unroll
      for (int qs = 0; qs < 8; ++qs) {
        int sq = (qs + r + (r >> 3)) & 7;
        float4 d4 = *reinterpret_cast<float4*>(&Dl[r * 32 + sq * 4]);
        uh += a_l[qs * 4 + 0] * d4.x + a_l[qs * 4 + 1] * d4.y
            + a_l[qs * 4 + 2] * d4.z + a_l[qs * 4 + 3] * d4.w;
      }
      float rr = un_r - uh;
      r_l[t] = rr;
      float rp = redx64(rr * rr);
      if ((t & 63) == 0) red[t >> 6] = rp;
    }
    __syncthreads(); // B2: r_l, red visible
    err = sqrtf(red[0] + red[1]);
    gate = sigmoidf_(gpart + err * wge);
    // prefetch next step
    const int ljn = (lj + 1 < slen) ? (lj + 1) : lj;
    const int jn = j0 + ljn;
    float pfN[8];
    load_cand8(cand, ((size_t)ljn * BB + b) * 4096 + (size_t)c * 128 + rb * 8, pfN);
    float unN = (t < DMD) ? chunk_h[((size_t)b * NCH + jn) * DMD + t] : 0.f;
    float aColN = a_gg[((size_t)jn * BB + b) * 32 + c];
    float a32N = (t < 32) ? a_gg[((size_t)jn * BB + b) * 32 + t] : 0.f;
    float gpN = gpart_g[(size_t)jn * BB + b];
    float vldN = validf[(size_t)jn * BB + b];
    // D update (registers; r_l via aligned b128)
    float rr8[8];
    *reinterpret_cast<float4*>(&rr8[0]) = *reinterpret_cast<float4*>(&r_l[rb * 8]);
    *reinterpret_cast<float4*>(&rr8[4]) = *reinterpret_cast<float4*>(&r_l[rb * 8 + 4]);
    float dl[8], dn[8];
    float sl = 0.f, sc = 0.f;
    #pragma unroll
    for (int i = 0; i < 8; ++i) {
      dl[i] = Dv[i] + 0.03f * rr8[i] * a_col;
      sl += dl[i] * dl[i];
      sc += pf[i] * pf[i];
    }
    sl = redx16(sl); sc = redx16(sc);
    float il = 1.f / fmaxf(sqrtf(sl), 1e-12f);
    float ic = 1.f / fmaxf(sqrtf(sc), 1e-12f);
    float g1 = 1.f - gate;
    float sn = 0.f;
    #pragma unroll
    for (int i = 0; i < 8; ++i) { dn[i] = g1 * dl[i] * il + gate * pf[i] * ic; sn += dn[i] * dn[i]; }
    sn = redx16(sn);
    float inn = 1.f / fmaxf(sqrtf(sn), 1e-12f);
    const bool vb = (vld != 0.f);
    #pragma unroll
    for (int i = 0; i < 8; ++i) {
      if (vb) Dv[i] = dn[i] * inn;
      int dd = rb * 8 + i;
      Dl[dd * 32 + DSWZ(c, dd)] = Dv[i];
    }
    if (t < 32) a_l[t] = a32N;
    #pragma unroll
    for (int q = 0; q < 8; ++q) pf[q] = pfN[q];
    un_r = unN; a_col = aColN; gpart = gpN; vld = vldN;
  }
  __syncthreads();
  // persist D from registers (row-major global)
  #pragma unroll
  for (int i = 0; i < 8; ++i)
    Dst[(size_t)b * 4096 + (rb * 8 + i) * 32 + c] = Dv[i];
  if (!doHead) return;
  // ---- head ----
  if (t < 32) a_l[t] = c_g[((size_t)(NCH - 1) * BB + b) * 32 + t];  // c_last
  __syncthreads();
  if (t < DMD) {
    const int r = t;
    float z = 0.f;
    #pragma unroll
    for (int qs = 0; qs < 8; ++qs) {
      int sq = (qs + r + (r >> 3)) & 7;
      float4 d4 = *reinterpret_cast<float4*>(&Dl[r * 32 + sq * 4]);
      z += a_l[qs * 4 + 0] * d4.x + a_l[qs * 4 + 1] * d4.y
         + a_l[qs * 4 + 2] * d4.z + a_l[qs * 4 + 3] * d4.w;
    }
    feat[t] = z;
    feat[160 + t] = smean[b * DMD + t];
    feat[288 + t] = smax[b * DMD + t];
  }
  if (t >= 128 && t < 160) feat[t] = a_l[t - 128];
  if (t == 0) { feat[416] = err; feat[417] = gate; }
  __syncthreads();
  float fv = (t < FEATN) ? feat[t] : 0.f;
  float ws1 = redx64(fv);
  if ((t & 63) == 0) red[t >> 6] = ws1;
  __syncthreads();
  float tot = 0.f;
  #pragma unroll
  for (int w = 0; w < 8; ++w) tot += red[w];
  float mean = tot * (1.f / 418.f);
  float dvv = (t < FEATN) ? (fv - mean) : 0.f;
  float ws2 = redx64(dvv * dvv);
  __syncthreads();
  if ((t & 63) == 0) red[t >> 6] = ws2;
  __syncthreads();
  float vtot = 0.f;
  #pragma unroll
  for (int w = 0; w < 8; ++w) vtot += red[w];
  float rs = rsqrtf(vtot * (1.f / 418.f) + 1e-5f);
  if (t < FEATN) featn[t] = (fv - mean) * rs * clw[t] + clb[t];
  __syncthreads();
  if (t < 256) {
    float acc = f1b[t];
    for (int f = 0; f < FEATN; ++f) acc += featn[f] * f1w[(size_t)f * 256 + t];
    h1[t] = acc * 0.5f * (1.f + erff(acc * 0.70710678f));
  }
  __syncthreads();
  if (t < 8) {
    float acc = f2b[t];
    #pragma unroll 8
    for (int i = 0; i < 256; ++i) acc += h1[i] * f2w[i * 8 + t];
    out[b * 8 + t] = acc;
  }
}

// ---------------- launch ----------------
extern "C" void kernel_launch(void* const* d_in, const int* in_sizes, int n_in,
                              void* d_out, int out_size, void* d_ws, size_t ws_size,
                              hipStream_t stream) {
  const int*   tokens = (const int*)d_in[0];
  const float* emb    = (const float*)d_in[1];
  const float* in_w   = (const float*)d_in[2];
  const float* in_b   = (const float*)d_in[3];
  const float* c1w    = (const float*)d_in[4];
  const float* c1b    = (const float*)d_in[5];
  const float* c2w    = (const float*)d_in[6];
  const float* c2b    = (const float*)d_in[7];
  const float* op_w   = (const float*)d_in[8];
  const float* op_b   = (const float*)d_in[9];
  const float* on_w   = (const float*)d_in[10];
  const float* on_b   = (const float*)d_in[11];
  const float* base_D = (const float*)d_in[12];
  const float* wcu    = (const float*)d_in[13];
  const float* wcc    = (const float*)d_in[14];
  const float* wcdu   = (const float*)d_in[15];
  const float* bcdu   = (const float*)d_in[16];
  const float* wcdc   = (const float*)d_in[17];
  const float* bcdc   = (const float*)d_in[18];
  const float* wg     = (const float*)d_in[19];
  const float* bg     = (const float*)d_in[20];
  const float* un_w   = (const float*)d_in[21];
  const float* un_b   = (const float*)d_in[22];
  const float* cn_w   = (const float*)d_in[23];
  const float* cn_b   = (const float*)d_in[24];
  const float* cl_w   = (const float*)d_in[25];
  const float* cl_b   = (const float*)d_in[26];
  const float* f1w    = (const float*)d_in[27];
  const float* f1b    = (const float*)d_in[28];
  const float* f2w    = (const float*)d_in[29];
  const float* f2b    = (const float*)d_in[30];

  // ---- adaptive workspace layout ----
  const size_t CHEL = (size_t)BB * NCH * DMD;
  const size_t NB   = (size_t)NCH * BB;
  size_t fixedFloats = CHEL + NB + NB * 32 + NB
                     + (size_t)BB * 64 * DMD * 2 + (size_t)BB * 64
                     + (size_t)BB * DMD * 2 + (size_t)BB * 4096
                     + NB * 32 + NB * 32 + NB;
  const size_t WFRAG  = 655360ull;                      // cand-weight ushorts per copy
  const size_t W3FR   = 98304ull;                       // conv3 frag ushorts per copy
  const size_t W5FR   = 163840ull;                      // conv5 frag ushorts per copy
  const size_t WSWZ_BYTES = (2ull * WFRAG + 2ull * W3FR + 2ull * W5FR) * 2ull;
  const size_t FIXED_BYTES = fixedFloats * 4 + WSWZ_BYTES;
  const size_t SEG_UNIT = (size_t)BB * 4096 * 2;        // 512 KB per step
  int S = 512;
  while (S > 1 && (size_t)S * SEG_UNIT + FIXED_BYTES > ws_size) S >>= 1;

  unsigned short* cand = (unsigned short*)d_ws;
  unsigned short* Whi  = (unsigned short*)((char*)d_ws + (size_t)S * SEG_UNIT);
  unsigned short* Wlo  = Whi + WFRAG;
  unsigned short* W3hi = Wlo + WFRAG;
  unsigned short* W3lo = W3hi + W3FR;
  unsigned short* W5hi = W3lo + W3FR;
  unsigned short* W5lo = W5hi + W5FR;
  float* base = (float*)(W5lo + W5FR);
  float* chunk_h = base; base += CHEL;
  float* validf  = base; base += NB;
  float* lgu     = base; base += NB * 32;
  float* gu      = base; base += NB;
  float* spsum   = base; base += (size_t)BB * 64 * DMD;
  float* spmax   = base; base += (size_t)BB * 64 * DMD;
  float* spcnt   = base; base += (size_t)BB * 64;
  float* smean   = base; base += (size_t)BB * DMD;
  float* smaxv   = base; base += (size_t)BB * DMD;
  float* Dst     = base; base += (size_t)BB * 4096;
  float* a_g     = base; base += NB * 32;
  float* c_g     = base; base += NB * 32;
  float* gpart   = base; base += NB;
  float* out = (float*)d_out;
  fprintf(stderr, "[hsfc69] ws_size=%zu fixed=%zu S=%d total=%zu\n",
          ws_size, FIXED_BYTES, S, FIXED_BYTES + (size_t)S * SEG_UNIT);

  k_prep_w<<<dim3(320), dim3(256), 0, stream>>>(wcdu, wcdc, Whi, Wlo);
  k_prep_conv<<<dim3(128), dim3(256), 0, stream>>>(c1w, c2w, W3hi, W3lo, W5hi, W5lo);
  k_front<<<dim3(64, BB), dim3(256), 0, stream>>>(
      tokens, emb, in_w, in_b, W3hi, W3lo, W5hi, W5lo, c1b, c2b,
      op_w, op_b, on_w, on_b, un_w, un_b, wcu, wg,
      chunk_h, validf, lgu, gu, spsum, spmax, spcnt);
  k_surface<<<dim3(BB), dim3(128), 0, stream>>>(spsum, spmax, spcnt, smean, smaxv);
  k_accrec<<<dim3(BB), dim3(64), 0, stream>>>(
      lgu, gu, validf, wcc, cn_w, cn_b, wg, bg, a_g, c_g, gpart);
  for (int j0 = 0; j0 < NCH; j0 += S) {
    k_cand_mfma<<<dim3(16, S), dim3(256), 0, stream>>>(
        chunk_h, c_g, Whi, Wlo, bcdu, bcdc, cand, j0);
    k_scan_seg<<<dim3(BB), dim3(512), 0, stream>>>(
        chunk_h, a_g, c_g, gpart, validf, cand, j0, S,
        wg, base_D, Dst, smean, smaxv, cl_w, cl_b, f1w, f1b, f2w, f2b, out);
  }
}